// Round 6
// baseline (372.364 us; speedup 1.0000x reference)
//
#include <hip/hip_runtime.h>
#include <math.h>

#define HID 64
#define HEADS 4
#define GR 64
#define NEG 0.2f
#define NB 8        // nodes per batch in fused layer-2 GEMM
#define NBKT_MAX 512
#define BK_SH 8     // 256 nodes per bucket
#define PART_T 2048 // edges per partition tile
// tmp edge pack: (dst & 255) << 17 | src   -- requires N < 2^17 (N=100000 ok)

__device__ __forceinline__ float lrelu(float v){ return v > 0.f ? v : NEG * v; }
__device__ __forceinline__ float elu_(float v){ return v > 0.f ? v : expm1f(v); }

// deg=1 (self-loop), zero pooled sums/counts; block 0 wave 0 also computes the
// attention-projection constants cvec = [cs0(4), cs1(4), cd0(4), cd1(4)].
// (must run EVERY call: harness does not re-poison ws between timed replays)
__global__ void k_init(int* deg, float* sums, int* counts, int N,
                       const float* __restrict__ W1, const float* __restrict__ as1,
                       const float* __restrict__ ad1, float* cvec){
    int i = blockIdx.x * blockDim.x + threadIdx.x;
    if (i < N) deg[i] = 1;
    if (i < GR * HID) sums[i] = 0.f;
    if (i < GR) counts[i] = 0;
    if (blockIdx.x == 0 && threadIdx.x < 64){
        int lane = threadIdx.x;
#pragma unroll
        for (int h = 0; h < HEADS; h++){
            int j = h * HID + lane;
            float s0 = W1[j]       * as1[j];
            float s1 = W1[256 + j] * as1[j];
            float d0 = W1[j]       * ad1[j];
            float d1 = W1[256 + j] * ad1[j];
#pragma unroll
            for (int off = 32; off; off >>= 1){
                s0 += __shfl_xor(s0, off, 64);
                s1 += __shfl_xor(s1, off, 64);
                d0 += __shfl_xor(d0, off, 64);
                d1 += __shfl_xor(d1, off, 64);
            }
            if (lane == 0){
                cvec[h] = s0; cvec[4 + h] = s1; cvec[8 + h] = d0; cvec[12 + h] = d1;
            }
        }
    }
}

// node-degree histogram only (bucket bases are derived from offs algebraically)
__global__ void k_hist(const int* __restrict__ dst, int E, int* deg){
    int stride = gridDim.x * blockDim.x;
    for (int i = blockIdx.x * blockDim.x + threadIdx.x; i < E; i += stride)
        atomicAdd(&deg[dst[i]], 1);
}

__global__ void k_scan1(const int* __restrict__ deg, int N, int* offs, int* bsum){
    __shared__ int sh[1024];
    int i = blockIdx.x * 1024 + threadIdx.x;
    int v = (i < N) ? deg[i] : 0;
    sh[threadIdx.x] = v;
    __syncthreads();
    for (int off = 1; off < 1024; off <<= 1){
        int t = (threadIdx.x >= off) ? sh[threadIdx.x - off] : 0;
        __syncthreads();
        sh[threadIdx.x] += t;
        __syncthreads();
    }
    if (i < N) offs[i] = sh[threadIdx.x] - v;
    if (threadIdx.x == 1023) bsum[blockIdx.x] = sh[1023];
}

// parallel exclusive scan of block sums (nb <= 1024)
__global__ void k_scan2(int* bsum, int nb){
    __shared__ int sh[1024];
    int t = threadIdx.x;
    int v = (t < nb) ? bsum[t] : 0;
    sh[t] = v;
    __syncthreads();
    for (int off = 1; off < 1024; off <<= 1){
        int u = (t >= off) ? sh[t - off] : 0;
        __syncthreads();
        sh[t] += u;
        __syncthreads();
    }
    if (t < nb) bsum[t] = sh[t] - v;
}

__global__ void k_scan3(int* offs, const int* __restrict__ bsum, int N, int Et){
    int i = blockIdx.x * 1024 + threadIdx.x;
    if (i < N) offs[i] += bsum[blockIdx.x];
    if (i == 0) offs[N] = Et;
}

// bucket bases from offs: bbase[b] = offs[b*256] - b*256 (strip self-loops);
// bbase[nbkt] = E. bcursor = bbase copy for partition reservation.
__global__ void k_bsetup(const int* __restrict__ offs, int N, int E, int nbkt,
                         int* bbase, int* bcursor){
    int t = threadIdx.x + blockIdx.x * blockDim.x;
    if (t < nbkt){
        int n0 = t << BK_SH;
        int v = offs[n0] - n0;
        bbase[t] = v;
        bcursor[t] = v;
    }
    if (t == nbkt) bbase[t] = E;
}

// staged partition: per-tile LDS bucket count -> one global reserve per
// (block,bucket) -> scatter packed u32 (dloc<<17|src) into block-private runs.
__global__ void __launch_bounds__(256)
k_part(const int* __restrict__ src, const int* __restrict__ dst, int E,
       int* bcursor, unsigned int* __restrict__ tmp){
    __shared__ int bh[NBKT_MAX];
    __shared__ int gbl[NBKT_MAX];
    int tid = threadIdx.x;
    int base = blockIdx.x * PART_T;
    for (int b = tid; b < NBKT_MAX; b += 256) bh[b] = 0;
    __syncthreads();
#pragma unroll
    for (int r = 0; r < PART_T / 256; r++){
        int i = base + r * 256 + tid;
        if (i < E) atomicAdd(&bh[dst[i] >> BK_SH], 1);
    }
    __syncthreads();
    for (int b = tid; b < NBKT_MAX; b += 256){
        int c = bh[b];
        gbl[b] = c ? atomicAdd(&bcursor[b], c) : 0;
        bh[b] = 0;
    }
    __syncthreads();
#pragma unroll
    for (int r = 0; r < PART_T / 256; r++){
        int i = base + r * 256 + tid;
        if (i < E){
            int s = src[i], d = dst[i];
            int b = d >> BK_SH;
            int rank = atomicAdd(&bh[b], 1);
            tmp[(size_t)(gbl[b] + rank)] =
                ((unsigned)(d & ((1 << BK_SH) - 1)) << 17) | (unsigned)s;
        }
    }
}

// per-bucket CSR emit: block-private ssrc region, LDS per-node rank counters,
// self-loop injected at offs[n] (position 0 of each node's range).
__global__ void __launch_bounds__(256)
k_csr(const unsigned int* __restrict__ tmp, const int* __restrict__ bbase,
      const int* __restrict__ offs, int N, int* __restrict__ ssrc){
    __shared__ int rc[256];
    int b = blockIdx.x, tid = threadIdx.x;
    int n0 = b << BK_SH;
    int nloc = min(256, N - n0);
    if (tid < nloc){
        rc[tid] = 0;
        int n = n0 + tid;
        ssrc[offs[n]] = n;     // self-loop first
    }
    __syncthreads();
    int beg = bbase[b], cnt = bbase[b + 1] - beg;
    for (int i = tid; i < cnt; i += 256){
        unsigned int e = tmp[beg + i];
        int dloc = (int)(e >> 17);
        int s = (int)(e & 0x1FFFFu);
        int pos = offs[n0 + dloc] + 1 + atomicAdd(&rc[dloc], 1);
        ssrc[pos] = s;
    }
}

// layer-1 aggregation via rank-2 trick: thread per dst node, gather only x[src]
// (8B/edge, cache-resident). Edge loop unrolled x8 for per-lane MLP (only
// ~1.5 waves/SIMD at N=100k, so ILP is the latency-hiding mechanism).
__global__ void k_agg1s(const float* __restrict__ x, const int* __restrict__ offs,
                        const int* __restrict__ ssrc, const float* __restrict__ cvec,
                        int N, float4* Sa, float4* Sb, float4* Sc){
    int n = blockIdx.x * blockDim.x + threadIdx.x;
    if (n >= N) return;
    float4 cs0 = ((const float4*)cvec)[0];
    float4 cs1 = ((const float4*)cvec)[1];
    float4 cd0 = ((const float4*)cvec)[2];
    float4 cd1 = ((const float4*)cvec)[3];
    float c0[4] = {cs0.x, cs0.y, cs0.z, cs0.w};
    float c1[4] = {cs1.x, cs1.y, cs1.z, cs1.w};
    float2 xn = ((const float2*)x)[n];
    float ad[4] = {xn.x*cd0.x + xn.y*cd1.x, xn.x*cd0.y + xn.y*cd1.y,
                   xn.x*cd0.z + xn.y*cd1.z, xn.x*cd0.w + xn.y*cd1.w};
    float A0[4] = {0,0,0,0}, A1[4] = {0,0,0,0}, D[4] = {0,0,0,0};
    int beg = offs[n], end = offs[n + 1];
    int j = beg;
    for (; j + 8 <= end; j += 8){
        int si[8];
#pragma unroll
        for (int u = 0; u < 8; u++) si[u] = ssrc[j + u];
        float2 xs[8];
#pragma unroll
        for (int u = 0; u < 8; u++) xs[u] = ((const float2*)x)[si[u]];
#pragma unroll
        for (int h = 0; h < HEADS; h++){
#pragma unroll
            for (int u = 0; u < 8; u++){
                float w = __expf(lrelu(xs[u].x * c0[h] + xs[u].y * c1[h] + ad[h]));
                A0[h] += w * xs[u].x;
                A1[h] += w * xs[u].y;
                D[h]  += w;
            }
        }
    }
    if (j + 4 <= end){
        int si[4];
#pragma unroll
        for (int u = 0; u < 4; u++) si[u] = ssrc[j + u];
        float2 xs[4];
#pragma unroll
        for (int u = 0; u < 4; u++) xs[u] = ((const float2*)x)[si[u]];
#pragma unroll
        for (int h = 0; h < HEADS; h++){
#pragma unroll
            for (int u = 0; u < 4; u++){
                float w = __expf(lrelu(xs[u].x * c0[h] + xs[u].y * c1[h] + ad[h]));
                A0[h] += w * xs[u].x;
                A1[h] += w * xs[u].y;
                D[h]  += w;
            }
        }
        j += 4;
    }
    for (; j < end; j++){
        int s = ssrc[j];
        float2 xs = ((const float2*)x)[s];
#pragma unroll
        for (int h = 0; h < HEADS; h++){
            float e = xs.x * c0[h] + xs.y * c1[h] + ad[h];
            float w = __expf(lrelu(e));
            A0[h] += w * xs.x;
            A1[h] += w * xs.y;
            D[h]  += w;
        }
    }
    Sa[n] = make_float4(A0[0], A0[1], A0[2], A0[3]);
    Sb[n] = make_float4(A1[0], A1[1], A1[2], A1[3]);
    Sc[n] = make_float4(D[0],  D[1],  D[2],  D[3]);
}

// Fused: h1 row computed in-register from 12 scalars, GEMM vs W2 (W2 in VGPRs,
// 4-wave k-split), LDS broadcast of h, LDS partial reduce, attention dots.
__global__ void __launch_bounds__(256)
k_l2fused(const float* __restrict__ Saf, const float* __restrict__ Sbf,
          const float* __restrict__ Scf, const float* __restrict__ W1,
          const float* __restrict__ b1, const float* __restrict__ W2,
          const float* __restrict__ as2, const float* __restrict__ ad2,
          int N, float* __restrict__ xh2, float* __restrict__ asrc,
          float* __restrict__ adst){
    __shared__ float hS[NB][256];
    __shared__ float partS[4][NB][64];
    int lane = threadIdx.x & 63, w = threadIdx.x >> 6;
    int kk = w * 64 + lane;
    float w2r[64];
#pragma unroll
    for (int j = 0; j < 64; j++) w2r[j] = W2[(w * 64 + j) * 64 + lane];
    float w10 = W1[kk], w11 = W1[256 + kk], b1k = b1[kk];
    float asw = as2[lane], adw = ad2[lane];

    int nbatches = (N + NB - 1) / NB;
    for (int b = blockIdx.x; b < nbatches; b += gridDim.x){
        int n0 = b * NB;
#pragma unroll
        for (int m = 0; m < NB; m++){
            int n = n0 + m;
            if (n < N){
                float A0 = Saf[n * 4 + w], A1 = Sbf[n * 4 + w], Dv = Scf[n * 4 + w];
                float u = (A0 * w10 + A1 * w11) / Dv + b1k;
                hS[m][kk] = elu_(u);
            }
        }
        __syncthreads();
#pragma unroll
        for (int m = 0; m < NB; m++){
            float acc = 0.f;
            const float4* hp = (const float4*)&hS[m][w * 64];
#pragma unroll
            for (int q = 0; q < 16; q++){
                float4 hv = hp[q];
                acc += hv.x * w2r[4*q] + hv.y * w2r[4*q+1]
                     + hv.z * w2r[4*q+2] + hv.w * w2r[4*q+3];
            }
            partS[w][m][lane] = acc;
        }
        __syncthreads();
        for (int m = w; m < NB; m += 4){
            int n = n0 + m;
            if (n < N){
                float acc = partS[0][m][lane] + partS[1][m][lane]
                          + partS[2][m][lane] + partS[3][m][lane];
                xh2[(size_t)n * 64 + lane] = acc;
                float ps = acc * asw, pd = acc * adw;
#pragma unroll
                for (int off = 32; off; off >>= 1){
                    ps += __shfl_xor(ps, off, 64);
                    pd += __shfl_xor(pd, off, 64);
                }
                if (lane == 0){ asrc[n] = ps; adst[n] = pd; }
            }
        }
        __syncthreads();
    }
}

// layer-2 aggregation fused with global mean pool. Edge loop unrolled x8 so
// ~16 loads are in flight per wave (covers ~600cyc L3 gather latency with
// 8 waves/SIMD x ~80cyc of math each).
__global__ void __launch_bounds__(256, 8)
k_agg2p(const float* __restrict__ xh2, const float* __restrict__ asrc,
        const float* __restrict__ adst, const int* __restrict__ offs,
        const int* __restrict__ ssrc, const float* __restrict__ b2,
        const int* __restrict__ batch, int N,
        float* sums, int* counts){
    int lane = threadIdx.x & 63, wv = threadIdx.x >> 6;  // 4 waves/block
    int wid = blockIdx.x * 4 + wv;
    int nw = gridDim.x * 4;
    int chunk = (N + nw - 1) / nw;
    int beg = wid * chunk, end = min(beg + chunk, N);
    if (beg >= end) return;
    float b2l = b2[lane];
    float pacc = 0.f; int pcnt = 0; int cur = batch[beg];
    for (int n = beg; n < end; n++){
        float ad = adst[n];
        float acc = 0.f, den = 0.f;
        int e0 = offs[n], e1 = offs[n + 1];
        int j = e0;
        for (; j + 8 <= e1; j += 8){
            int s0 = ssrc[j],   s1 = ssrc[j+1], s2 = ssrc[j+2], s3 = ssrc[j+3];
            int s4 = ssrc[j+4], s5 = ssrc[j+5], s6 = ssrc[j+6], s7 = ssrc[j+7];
            float a0 = asrc[s0], a1 = asrc[s1], a2 = asrc[s2], a3 = asrc[s3];
            float a4 = asrc[s4], a5 = asrc[s5], a6 = asrc[s6], a7 = asrc[s7];
            float r0 = xh2[(size_t)s0 * 64 + lane];
            float r1 = xh2[(size_t)s1 * 64 + lane];
            float r2 = xh2[(size_t)s2 * 64 + lane];
            float r3 = xh2[(size_t)s3 * 64 + lane];
            float r4 = xh2[(size_t)s4 * 64 + lane];
            float r5 = xh2[(size_t)s5 * 64 + lane];
            float r6 = xh2[(size_t)s6 * 64 + lane];
            float r7 = xh2[(size_t)s7 * 64 + lane];
            float w0 = __expf(lrelu(a0 + ad));
            float w1 = __expf(lrelu(a1 + ad));
            float w2 = __expf(lrelu(a2 + ad));
            float w3 = __expf(lrelu(a3 + ad));
            float w4 = __expf(lrelu(a4 + ad));
            float w5 = __expf(lrelu(a5 + ad));
            float w6 = __expf(lrelu(a6 + ad));
            float w7 = __expf(lrelu(a7 + ad));
            acc += w0*r0 + w1*r1 + w2*r2 + w3*r3 + w4*r4 + w5*r5 + w6*r6 + w7*r7;
            den += w0 + w1 + w2 + w3 + w4 + w5 + w6 + w7;
        }
        if (j + 4 <= e1){
            int s0 = ssrc[j], s1 = ssrc[j+1], s2 = ssrc[j+2], s3 = ssrc[j+3];
            float a0 = asrc[s0], a1 = asrc[s1], a2 = asrc[s2], a3 = asrc[s3];
            float r0 = xh2[(size_t)s0 * 64 + lane];
            float r1 = xh2[(size_t)s1 * 64 + lane];
            float r2 = xh2[(size_t)s2 * 64 + lane];
            float r3 = xh2[(size_t)s3 * 64 + lane];
            float w0 = __expf(lrelu(a0 + ad));
            float w1 = __expf(lrelu(a1 + ad));
            float w2 = __expf(lrelu(a2 + ad));
            float w3 = __expf(lrelu(a3 + ad));
            acc += w0*r0 + w1*r1 + w2*r2 + w3*r3;
            den += w0 + w1 + w2 + w3;
            j += 4;
        }
        for (; j < e1; j++){
            int s = ssrc[j];
            float wgt = __expf(lrelu(asrc[s] + ad));
            acc += wgt * xh2[(size_t)s * 64 + lane];
            den += wgt;
        }
        float h2v = elu_(acc / den + b2l);
        int g = batch[n];
        if (g != cur){
            atomicAdd(&sums[cur * HID + lane], pacc);
            if (lane == 0) atomicAdd(&counts[cur], pcnt);
            pacc = 0.f; pcnt = 0; cur = g;
        }
        pacc += h2v; pcnt++;
    }
    atomicAdd(&sums[cur * HID + lane], pacc);
    if (lane == 0) atomicAdd(&counts[cur], pcnt);
}

__global__ void k_final(const float* __restrict__ sums, const int* __restrict__ counts,
                        const float* __restrict__ Wl, const float* __restrict__ bl,
                        float* out){
    int t = threadIdx.x;
    if (t >= GR * 2) return;
    int g = t >> 1, task = t & 1;
    float c = (float)max(counts[g], 1);
    float acc = 0.f;
#pragma unroll
    for (int k = 0; k < HID; k++)
        acc += (sums[g * HID + k] / c) * Wl[k * 2 + task];
    out[t] = acc + bl[task];
}

extern "C" void kernel_launch(void* const* d_in, const int* in_sizes, int n_in,
                              void* d_out, int out_size, void* d_ws, size_t ws_size,
                              hipStream_t stream) {
    const float* x    = (const float*)d_in[0];
    const int*   ei   = (const int*)  d_in[1];
    const int*   batch= (const int*)  d_in[2];
    const float* W1   = (const float*)d_in[3];
    const float* as1  = (const float*)d_in[4];
    const float* ad1  = (const float*)d_in[5];
    const float* b1   = (const float*)d_in[6];
    const float* W2   = (const float*)d_in[7];
    const float* as2  = (const float*)d_in[8];
    const float* ad2  = (const float*)d_in[9];
    const float* b2   = (const float*)d_in[10];
    const float* Wl   = (const float*)d_in[11];
    const float* bl   = (const float*)d_in[12];
    float* out = (float*)d_out;

    int N  = in_sizes[0] / 2;
    int E  = in_sizes[1] / 2;
    int Et = E + N;
    const int* srcp = ei;
    const int* dstp = ei + E;

    char* p = (char*)d_ws;
    auto alloc = [&](size_t bytes)->char* {
        char* r = p; p += (bytes + 255) & ~(size_t)255; return r;
    };
    int*    deg    = (int*)   alloc((size_t)N * 4);
    int*    offs   = (int*)   alloc((size_t)(N + 1) * 4);
    int*    bsum   = (int*)   alloc(1024 * 4);
    int*    bbase  = (int*)   alloc((NBKT_MAX + 1) * 4);
    int*    bcursor= (int*)   alloc(NBKT_MAX * 4);
    int*    ssrc   = (int*)   alloc((size_t)Et * 4);
    unsigned int* tmp = (unsigned int*)alloc((size_t)E * 4);
    float*  cvec   = (float*) alloc(16 * 4);
    float4* Sa     = (float4*)alloc((size_t)N * 16);
    float4* Sb     = (float4*)alloc((size_t)N * 16);
    float4* Sc     = (float4*)alloc((size_t)N * 16);
    float*  asrc2  = (float*) alloc((size_t)N * 4);
    float*  adst2  = (float*) alloc((size_t)N * 4);
    float*  sums   = (float*) alloc((size_t)GR * HID * 4);
    int*    counts = (int*)   alloc((size_t)GR * 4);
    float*  xh2    = (float*) alloc((size_t)N * 64 * 4);

    int nb1024 = (N + 1023) / 1024;
    int nbkt   = (N + 255) >> BK_SH;

    k_init <<<(N + 255) / 256, 256, 0, stream>>>(deg, sums, counts, N, W1, as1, ad1, cvec);
    k_hist <<<1024, 256, 0, stream>>>(dstp, E, deg);
    k_scan1<<<nb1024, 1024, 0, stream>>>(deg, N, offs, bsum);
    k_scan2<<<1, 1024, 0, stream>>>(bsum, nb1024);
    k_scan3<<<nb1024, 1024, 0, stream>>>(offs, bsum, N, Et);
    k_bsetup<<<2, 512, 0, stream>>>(offs, N, E, nbkt, bbase, bcursor);
    k_part <<<(E + PART_T - 1) / PART_T, 256, 0, stream>>>(srcp, dstp, E, bcursor, tmp);
    k_csr  <<<nbkt, 256, 0, stream>>>(tmp, bbase, offs, N, ssrc);

    k_agg1s<<<(N + 255) / 256, 256, 0, stream>>>(x, offs, ssrc, cvec, N, Sa, Sb, Sc);
    k_l2fused<<<2048, 256, 0, stream>>>((const float*)Sa, (const float*)Sb,
                                        (const float*)Sc, W1, b1, W2, as2, ad2,
                                        N, xh2, asrc2, adst2);
    k_agg2p<<<4096, 256, 0, stream>>>(xh2, asrc2, adst2, offs, ssrc, b2,
                                      batch, N, sums, counts);
    k_final<<<1, 128, 0, stream>>>(sums, counts, Wl, bl, out);
}

// Round 7
// 276.846 us; speedup vs baseline: 1.3450x; 1.3450x over previous
//
#include <hip/hip_runtime.h>
#include <hip/hip_fp16.h>
#include <math.h>

#define HID 64
#define HEADS 4
#define GR 64
#define NEG 0.2f
#define NB 8        // nodes per batch in fused layer-2 GEMM
#define NBKT_MAX 512
#define BK_SH 8     // 256 nodes per bucket
#define PART_T 2048 // edges per partition tile
// tmp edge pack: (dst & 255) << 17 | src   -- requires N < 2^17 (N=100000 ok)

__device__ __forceinline__ float lrelu(float v){ return v > 0.f ? v : NEG * v; }
__device__ __forceinline__ float elu_(float v){ return v > 0.f ? v : expm1f(v); }

// zero pooled sums/counts/bucket-counts; block 0 wave 0 also computes the
// attention-projection constants cvec = [cs0(4), cs1(4), cd0(4), cd1(4)].
// (must run EVERY call: harness does not re-poison ws between timed replays)
__global__ void k_init(float* sums, int* counts, int* bcnt,
                       const float* __restrict__ W1, const float* __restrict__ as1,
                       const float* __restrict__ ad1, float* cvec){
    int i = blockIdx.x * blockDim.x + threadIdx.x;
    if (i < GR * HID) sums[i] = 0.f;
    if (i < GR) counts[i] = 0;
    if (i < NBKT_MAX) bcnt[i] = 0;
    if (blockIdx.x == 0 && threadIdx.x < 64){
        int lane = threadIdx.x;
#pragma unroll
        for (int h = 0; h < HEADS; h++){
            int j = h * HID + lane;
            float s0 = W1[j]       * as1[j];
            float s1 = W1[256 + j] * as1[j];
            float d0 = W1[j]       * ad1[j];
            float d1 = W1[256 + j] * ad1[j];
#pragma unroll
            for (int off = 32; off; off >>= 1){
                s0 += __shfl_xor(s0, off, 64);
                s1 += __shfl_xor(s1, off, 64);
                d0 += __shfl_xor(d0, off, 64);
                d1 += __shfl_xor(d1, off, 64);
            }
            if (lane == 0){
                cvec[h] = s0; cvec[4 + h] = s1; cvec[8 + h] = d0; cvec[12 + h] = d1;
            }
        }
    }
}

// bucket-level histogram only (LDS-staged; per-node degrees derived in k_csr2)
__global__ void k_histB(const int* __restrict__ dst, int E, int* bcnt){
    __shared__ int bh[NBKT_MAX];
    for (int b = threadIdx.x; b < NBKT_MAX; b += blockDim.x) bh[b] = 0;
    __syncthreads();
    int stride = gridDim.x * blockDim.x;
    for (int i = blockIdx.x * blockDim.x + threadIdx.x; i < E; i += stride)
        atomicAdd(&bh[dst[i] >> BK_SH], 1);
    __syncthreads();
    for (int b = threadIdx.x; b < NBKT_MAX; b += blockDim.x)
        if (bh[b]) atomicAdd(&bcnt[b], bh[b]);
}

// exclusive scan of bucket counts -> bucket bases + partition cursors.
// bbase[nbkt] == E automatically (total of counts).
__global__ void k_bscan(const int* __restrict__ bcnt, int* bbase, int* bcursor){
    __shared__ int sh[NBKT_MAX];
    int t = threadIdx.x;     // 512 threads
    int v = bcnt[t];
    sh[t] = v;
    __syncthreads();
    for (int off = 1; off < NBKT_MAX; off <<= 1){
        int u = (t >= off) ? sh[t - off] : 0;
        __syncthreads();
        sh[t] += u;
        __syncthreads();
    }
    bbase[t] = sh[t] - v;
    bcursor[t] = sh[t] - v;
    if (t == NBKT_MAX - 1) bbase[NBKT_MAX] = sh[t];
}

// staged partition: per-tile LDS bucket count -> one global reserve per
// (block,bucket) -> scatter packed u32 (dloc<<17|src) into block-private runs.
__global__ void __launch_bounds__(256)
k_part(const int* __restrict__ src, const int* __restrict__ dst, int E,
       int* bcursor, unsigned int* __restrict__ tmp){
    __shared__ int bh[NBKT_MAX];
    __shared__ int gbl[NBKT_MAX];
    int tid = threadIdx.x;
    int base = blockIdx.x * PART_T;
    for (int b = tid; b < NBKT_MAX; b += 256) bh[b] = 0;
    __syncthreads();
#pragma unroll
    for (int r = 0; r < PART_T / 256; r++){
        int i = base + r * 256 + tid;
        if (i < E) atomicAdd(&bh[dst[i] >> BK_SH], 1);
    }
    __syncthreads();
    for (int b = tid; b < NBKT_MAX; b += 256){
        int c = bh[b];
        gbl[b] = c ? atomicAdd(&bcursor[b], c) : 0;
        bh[b] = 0;
    }
    __syncthreads();
#pragma unroll
    for (int r = 0; r < PART_T / 256; r++){
        int i = base + r * 256 + tid;
        if (i < E){
            int s = src[i], d = dst[i];
            int b = d >> BK_SH;
            int rank = atomicAdd(&bh[b], 1);
            tmp[(size_t)(gbl[b] + rank)] =
                ((unsigned)(d & ((1 << BK_SH) - 1)) << 17) | (unsigned)s;
        }
    }
}

// per-bucket CSR emit, now also deriving per-node offs locally:
// offs[n] = bbase[b] + n0 + excl_scan_local(deg_local+1)
// (bbase counts edges of earlier buckets, n0 counts their self-loops).
// Self-loop injected at offs[n], partitioned edges after it.
__global__ void __launch_bounds__(256)
k_csr2(const unsigned int* __restrict__ tmp, const int* __restrict__ bbase,
       int N, int Et, int* __restrict__ offs, int* __restrict__ ssrc){
    __shared__ int degl[256];
    __shared__ int rc[256];
    __shared__ int scan[256];
    __shared__ int ofl[256];
    int b = blockIdx.x, tid = threadIdx.x;
    int n0 = b << BK_SH;
    int nloc = min(256, N - n0);
    degl[tid] = 0; rc[tid] = 0;
    __syncthreads();
    int beg = bbase[b], cnt = bbase[b + 1] - beg;
    for (int i = tid; i < cnt; i += 256)
        atomicAdd(&degl[tmp[beg + i] >> 17], 1);
    __syncthreads();
    int v = (tid < nloc) ? degl[tid] + 1 : 0;
    scan[tid] = v;
    __syncthreads();
    for (int off = 1; off < 256; off <<= 1){
        int u = (tid >= off) ? scan[tid - off] : 0;
        __syncthreads();
        scan[tid] += u;
        __syncthreads();
    }
    int base = beg + n0;
    if (tid < nloc){
        int o = base + scan[tid] - v;   // exclusive
        ofl[tid] = o;
        offs[n0 + tid] = o;
        ssrc[o] = n0 + tid;             // self-loop first
    }
    if (b == 0 && tid == 0) offs[N] = Et;
    __syncthreads();
    for (int i = tid; i < cnt; i += 256){
        unsigned int e = tmp[beg + i];
        int dloc = (int)(e >> 17);
        int s = (int)(e & 0x1FFFFu);
        int pos = ofl[dloc] + 1 + atomicAdd(&rc[dloc], 1);
        ssrc[pos] = s;
    }
}

// layer-1 aggregation via rank-2 trick: thread per dst node, gather only x[src]
// (8B/edge, cache-resident). Edge loop unrolled x8 for per-lane MLP.
__global__ void k_agg1s(const float* __restrict__ x, const int* __restrict__ offs,
                        const int* __restrict__ ssrc, const float* __restrict__ cvec,
                        int N, float4* Sa, float4* Sb, float4* Sc){
    int n = blockIdx.x * blockDim.x + threadIdx.x;
    if (n >= N) return;
    float4 cs0 = ((const float4*)cvec)[0];
    float4 cs1 = ((const float4*)cvec)[1];
    float4 cd0 = ((const float4*)cvec)[2];
    float4 cd1 = ((const float4*)cvec)[3];
    float c0[4] = {cs0.x, cs0.y, cs0.z, cs0.w};
    float c1[4] = {cs1.x, cs1.y, cs1.z, cs1.w};
    float2 xn = ((const float2*)x)[n];
    float ad[4] = {xn.x*cd0.x + xn.y*cd1.x, xn.x*cd0.y + xn.y*cd1.y,
                   xn.x*cd0.z + xn.y*cd1.z, xn.x*cd0.w + xn.y*cd1.w};
    float A0[4] = {0,0,0,0}, A1[4] = {0,0,0,0}, D[4] = {0,0,0,0};
    int beg = offs[n], end = offs[n + 1];
    int j = beg;
    for (; j + 8 <= end; j += 8){
        int si[8];
#pragma unroll
        for (int u = 0; u < 8; u++) si[u] = ssrc[j + u];
        float2 xs[8];
#pragma unroll
        for (int u = 0; u < 8; u++) xs[u] = ((const float2*)x)[si[u]];
#pragma unroll
        for (int h = 0; h < HEADS; h++){
#pragma unroll
            for (int u = 0; u < 8; u++){
                float w = __expf(lrelu(xs[u].x * c0[h] + xs[u].y * c1[h] + ad[h]));
                A0[h] += w * xs[u].x;
                A1[h] += w * xs[u].y;
                D[h]  += w;
            }
        }
    }
    if (j + 4 <= end){
        int si[4];
#pragma unroll
        for (int u = 0; u < 4; u++) si[u] = ssrc[j + u];
        float2 xs[4];
#pragma unroll
        for (int u = 0; u < 4; u++) xs[u] = ((const float2*)x)[si[u]];
#pragma unroll
        for (int h = 0; h < HEADS; h++){
#pragma unroll
            for (int u = 0; u < 4; u++){
                float w = __expf(lrelu(xs[u].x * c0[h] + xs[u].y * c1[h] + ad[h]));
                A0[h] += w * xs[u].x;
                A1[h] += w * xs[u].y;
                D[h]  += w;
            }
        }
        j += 4;
    }
    for (; j < end; j++){
        int s = ssrc[j];
        float2 xs = ((const float2*)x)[s];
#pragma unroll
        for (int h = 0; h < HEADS; h++){
            float e = xs.x * c0[h] + xs.y * c1[h] + ad[h];
            float w = __expf(lrelu(e));
            A0[h] += w * xs.x;
            A1[h] += w * xs.y;
            D[h]  += w;
        }
    }
    Sa[n] = make_float4(A0[0], A0[1], A0[2], A0[3]);
    Sb[n] = make_float4(A1[0], A1[1], A1[2], A1[3]);
    Sc[n] = make_float4(D[0],  D[1],  D[2],  D[3]);
}

// Fused: h1 row computed in-register from 12 scalars, GEMM vs W2 (W2 in VGPRs,
// 4-wave k-split), LDS broadcast of h, LDS partial reduce, attention dots.
// xh2 stored as f16 (values only; attention logits stay fp32-exact).
__global__ void __launch_bounds__(256)
k_l2fused(const float* __restrict__ Saf, const float* __restrict__ Sbf,
          const float* __restrict__ Scf, const float* __restrict__ W1,
          const float* __restrict__ b1, const float* __restrict__ W2,
          const float* __restrict__ as2, const float* __restrict__ ad2,
          int N, __half* __restrict__ xh2, float* __restrict__ asrc,
          float* __restrict__ adst){
    __shared__ float hS[NB][256];
    __shared__ float partS[4][NB][64];
    int lane = threadIdx.x & 63, w = threadIdx.x >> 6;
    int kk = w * 64 + lane;
    float w2r[64];
#pragma unroll
    for (int j = 0; j < 64; j++) w2r[j] = W2[(w * 64 + j) * 64 + lane];
    float w10 = W1[kk], w11 = W1[256 + kk], b1k = b1[kk];
    float asw = as2[lane], adw = ad2[lane];

    int nbatches = (N + NB - 1) / NB;
    for (int b = blockIdx.x; b < nbatches; b += gridDim.x){
        int n0 = b * NB;
#pragma unroll
        for (int m = 0; m < NB; m++){
            int n = n0 + m;
            if (n < N){
                float A0 = Saf[n * 4 + w], A1 = Sbf[n * 4 + w], Dv = Scf[n * 4 + w];
                float u = (A0 * w10 + A1 * w11) / Dv + b1k;
                hS[m][kk] = elu_(u);
            }
        }
        __syncthreads();
#pragma unroll
        for (int m = 0; m < NB; m++){
            float acc = 0.f;
            const float4* hp = (const float4*)&hS[m][w * 64];
#pragma unroll
            for (int q = 0; q < 16; q++){
                float4 hv = hp[q];
                acc += hv.x * w2r[4*q] + hv.y * w2r[4*q+1]
                     + hv.z * w2r[4*q+2] + hv.w * w2r[4*q+3];
            }
            partS[w][m][lane] = acc;
        }
        __syncthreads();
        for (int m = w; m < NB; m += 4){
            int n = n0 + m;
            if (n < N){
                float acc = partS[0][m][lane] + partS[1][m][lane]
                          + partS[2][m][lane] + partS[3][m][lane];
                xh2[(size_t)n * 64 + lane] = __float2half(acc);
                float ps = acc * asw, pd = acc * adw;
#pragma unroll
                for (int off = 32; off; off >>= 1){
                    ps += __shfl_xor(ps, off, 64);
                    pd += __shfl_xor(pd, off, 64);
                }
                if (lane == 0){ asrc[n] = ps; adst[n] = pd; }
            }
        }
        __syncthreads();
    }
}

// layer-2 aggregation fused with global mean pool. f16 rows (128B/edge),
// fp32 logits & accumulation. Edge loop unrolled x4 (R5-proven config).
__global__ void k_agg2p(const __half* __restrict__ xh2, const float* __restrict__ asrc,
                        const float* __restrict__ adst, const int* __restrict__ offs,
                        const int* __restrict__ ssrc, const float* __restrict__ b2,
                        const int* __restrict__ batch, int N,
                        float* sums, int* counts){
    int lane = threadIdx.x & 63, wv = threadIdx.x >> 6;  // 4 waves/block
    int wid = blockIdx.x * 4 + wv;
    int nw = gridDim.x * 4;
    int chunk = (N + nw - 1) / nw;
    int beg = wid * chunk, end = min(beg + chunk, N);
    if (beg >= end) return;
    float b2l = b2[lane];
    float pacc = 0.f; int pcnt = 0; int cur = batch[beg];
    for (int n = beg; n < end; n++){
        float ad = adst[n];
        float acc = 0.f, den = 0.f;
        int e0 = offs[n], e1 = offs[n + 1];
        int j = e0;
        for (; j + 4 <= e1; j += 4){
            int s0 = ssrc[j], s1 = ssrc[j+1], s2 = ssrc[j+2], s3 = ssrc[j+3];
            float a0 = asrc[s0], a1 = asrc[s1], a2 = asrc[s2], a3 = asrc[s3];
            float r0 = __half2float(xh2[(size_t)s0 * 64 + lane]);
            float r1 = __half2float(xh2[(size_t)s1 * 64 + lane]);
            float r2 = __half2float(xh2[(size_t)s2 * 64 + lane]);
            float r3 = __half2float(xh2[(size_t)s3 * 64 + lane]);
            float w0 = __expf(lrelu(a0 + ad));
            float w1 = __expf(lrelu(a1 + ad));
            float w2 = __expf(lrelu(a2 + ad));
            float w3 = __expf(lrelu(a3 + ad));
            acc += w0 * r0 + w1 * r1 + w2 * r2 + w3 * r3;
            den += w0 + w1 + w2 + w3;
        }
        for (; j < e1; j++){
            int s = ssrc[j];
            float wgt = __expf(lrelu(asrc[s] + ad));
            acc += wgt * __half2float(xh2[(size_t)s * 64 + lane]);
            den += wgt;
        }
        float h2v = elu_(acc / den + b2l);
        int g = batch[n];
        if (g != cur){
            atomicAdd(&sums[cur * HID + lane], pacc);
            if (lane == 0) atomicAdd(&counts[cur], pcnt);
            pacc = 0.f; pcnt = 0; cur = g;
        }
        pacc += h2v; pcnt++;
    }
    atomicAdd(&sums[cur * HID + lane], pacc);
    if (lane == 0) atomicAdd(&counts[cur], pcnt);
}

__global__ void k_final(const float* __restrict__ sums, const int* __restrict__ counts,
                        const float* __restrict__ Wl, const float* __restrict__ bl,
                        float* out){
    int t = threadIdx.x;
    if (t >= GR * 2) return;
    int g = t >> 1, task = t & 1;
    float c = (float)max(counts[g], 1);
    float acc = 0.f;
#pragma unroll
    for (int k = 0; k < HID; k++)
        acc += (sums[g * HID + k] / c) * Wl[k * 2 + task];
    out[t] = acc + bl[task];
}

extern "C" void kernel_launch(void* const* d_in, const int* in_sizes, int n_in,
                              void* d_out, int out_size, void* d_ws, size_t ws_size,
                              hipStream_t stream) {
    const float* x    = (const float*)d_in[0];
    const int*   ei   = (const int*)  d_in[1];
    const int*   batch= (const int*)  d_in[2];
    const float* W1   = (const float*)d_in[3];
    const float* as1  = (const float*)d_in[4];
    const float* ad1  = (const float*)d_in[5];
    const float* b1   = (const float*)d_in[6];
    const float* W2   = (const float*)d_in[7];
    const float* as2  = (const float*)d_in[8];
    const float* ad2  = (const float*)d_in[9];
    const float* b2   = (const float*)d_in[10];
    const float* Wl   = (const float*)d_in[11];
    const float* bl   = (const float*)d_in[12];
    float* out = (float*)d_out;

    int N  = in_sizes[0] / 2;
    int E  = in_sizes[1] / 2;
    int Et = E + N;
    const int* srcp = ei;
    const int* dstp = ei + E;

    char* p = (char*)d_ws;
    auto alloc = [&](size_t bytes)->char* {
        char* r = p; p += (bytes + 255) & ~(size_t)255; return r;
    };
    int*    offs   = (int*)   alloc((size_t)(N + 1) * 4);
    int*    bcnt   = (int*)   alloc(NBKT_MAX * 4);
    int*    bbase  = (int*)   alloc((NBKT_MAX + 1) * 4);
    int*    bcursor= (int*)   alloc(NBKT_MAX * 4);
    int*    ssrc   = (int*)   alloc((size_t)Et * 4);
    unsigned int* tmp = (unsigned int*)alloc((size_t)E * 4);
    float*  cvec   = (float*) alloc(16 * 4);
    float4* Sa     = (float4*)alloc((size_t)N * 16);
    float4* Sb     = (float4*)alloc((size_t)N * 16);
    float4* Sc     = (float4*)alloc((size_t)N * 16);
    float*  asrc2  = (float*) alloc((size_t)N * 4);
    float*  adst2  = (float*) alloc((size_t)N * 4);
    float*  sums   = (float*) alloc((size_t)GR * HID * 4);
    int*    counts = (int*)   alloc((size_t)GR * 4);
    __half* xh2    = (__half*)alloc((size_t)N * 64 * 2);

    int nbkt = (N + 255) >> BK_SH;

    k_init <<<16, 256, 0, stream>>>(sums, counts, bcnt, W1, as1, ad1, cvec);
    k_histB<<<256, 256, 0, stream>>>(dstp, E, bcnt);
    k_bscan<<<1, NBKT_MAX, 0, stream>>>(bcnt, bbase, bcursor);
    k_part <<<(E + PART_T - 1) / PART_T, 256, 0, stream>>>(srcp, dstp, E, bcursor, tmp);
    k_csr2 <<<nbkt, 256, 0, stream>>>(tmp, bbase, N, Et, offs, ssrc);

    k_agg1s<<<(N + 255) / 256, 256, 0, stream>>>(x, offs, ssrc, cvec, N, Sa, Sb, Sc);
    k_l2fused<<<2048, 256, 0, stream>>>((const float*)Sa, (const float*)Sb,
                                        (const float*)Sc, W1, b1, W2, as2, ad2,
                                        N, xh2, asrc2, adst2);
    k_agg2p<<<2048, 256, 0, stream>>>(xh2, asrc2, adst2, offs, ssrc, b2,
                                      batch, N, sums, counts);
    k_final<<<1, 128, 0, stream>>>(sums, counts, Wl, bl, out);
}

// Round 8
// 275.736 us; speedup vs baseline: 1.3504x; 1.0040x over previous
//
#include <hip/hip_runtime.h>
#include <hip/hip_fp16.h>
#include <math.h>

#define HID 64
#define HEADS 4
#define GR 64
#define NEG 0.2f
#define NB 16       // nodes per batch in fused layer-2 GEMM
#define NBKT_MAX 512
#define BK_SH 8     // 256 nodes per bucket
#define PART_T 2048 // edges per partition tile
// tmp edge pack: (dst & 255) << 17 | src   -- requires N < 2^17 (N=100000 ok)

__device__ __forceinline__ float lrelu(float v){ return v > 0.f ? v : NEG * v; }
__device__ __forceinline__ float elu_(float v){ return v > 0.f ? v : expm1f(v); }

// zero pooled sums/counts/bucket-counts; block 0 wave 0 also computes the
// attention-projection constants cvec = [cs0(4), cs1(4), cd0(4), cd1(4)].
// (must run EVERY call: harness does not re-poison ws between timed replays)
__global__ void k_init(float* sums, int* counts, int* bcnt,
                       const float* __restrict__ W1, const float* __restrict__ as1,
                       const float* __restrict__ ad1, float* cvec){
    int i = blockIdx.x * blockDim.x + threadIdx.x;
    if (i < GR * HID) sums[i] = 0.f;
    if (i < GR) counts[i] = 0;
    if (i < NBKT_MAX) bcnt[i] = 0;
    if (blockIdx.x == 0 && threadIdx.x < 64){
        int lane = threadIdx.x;
#pragma unroll
        for (int h = 0; h < HEADS; h++){
            int j = h * HID + lane;
            float s0 = W1[j]       * as1[j];
            float s1 = W1[256 + j] * as1[j];
            float d0 = W1[j]       * ad1[j];
            float d1 = W1[256 + j] * ad1[j];
#pragma unroll
            for (int off = 32; off; off >>= 1){
                s0 += __shfl_xor(s0, off, 64);
                s1 += __shfl_xor(s1, off, 64);
                d0 += __shfl_xor(d0, off, 64);
                d1 += __shfl_xor(d1, off, 64);
            }
            if (lane == 0){
                cvec[h] = s0; cvec[4 + h] = s1; cvec[8 + h] = d0; cvec[12 + h] = d1;
            }
        }
    }
}

// bucket-level histogram only (LDS-staged; per-node degrees derived in k_csr2)
__global__ void k_histB(const int* __restrict__ dst, int E, int* bcnt){
    __shared__ int bh[NBKT_MAX];
    for (int b = threadIdx.x; b < NBKT_MAX; b += blockDim.x) bh[b] = 0;
    __syncthreads();
    int stride = gridDim.x * blockDim.x;
    for (int i = blockIdx.x * blockDim.x + threadIdx.x; i < E; i += stride)
        atomicAdd(&bh[dst[i] >> BK_SH], 1);
    __syncthreads();
    for (int b = threadIdx.x; b < NBKT_MAX; b += blockDim.x)
        if (bh[b]) atomicAdd(&bcnt[b], bh[b]);
}

// exclusive scan of bucket counts -> bucket bases + partition cursors.
__global__ void k_bscan(const int* __restrict__ bcnt, int* bbase, int* bcursor){
    __shared__ int sh[NBKT_MAX];
    int t = threadIdx.x;     // 512 threads
    int v = bcnt[t];
    sh[t] = v;
    __syncthreads();
    for (int off = 1; off < NBKT_MAX; off <<= 1){
        int u = (t >= off) ? sh[t - off] : 0;
        __syncthreads();
        sh[t] += u;
        __syncthreads();
    }
    bbase[t] = sh[t] - v;
    bcursor[t] = sh[t] - v;
    if (t == NBKT_MAX - 1) bbase[NBKT_MAX] = sh[t];
}

// staged partition: per-tile LDS bucket count -> one global reserve per
// (block,bucket) -> scatter packed u32 (dloc<<17|src) into block-private runs.
__global__ void __launch_bounds__(256)
k_part(const int* __restrict__ src, const int* __restrict__ dst, int E,
       int* bcursor, unsigned int* __restrict__ tmp){
    __shared__ int bh[NBKT_MAX];
    __shared__ int gbl[NBKT_MAX];
    int tid = threadIdx.x;
    int base = blockIdx.x * PART_T;
    for (int b = tid; b < NBKT_MAX; b += 256) bh[b] = 0;
    __syncthreads();
#pragma unroll
    for (int r = 0; r < PART_T / 256; r++){
        int i = base + r * 256 + tid;
        if (i < E) atomicAdd(&bh[dst[i] >> BK_SH], 1);
    }
    __syncthreads();
    for (int b = tid; b < NBKT_MAX; b += 256){
        int c = bh[b];
        gbl[b] = c ? atomicAdd(&bcursor[b], c) : 0;
        bh[b] = 0;
    }
    __syncthreads();
#pragma unroll
    for (int r = 0; r < PART_T / 256; r++){
        int i = base + r * 256 + tid;
        if (i < E){
            int s = src[i], d = dst[i];
            int b = d >> BK_SH;
            int rank = atomicAdd(&bh[b], 1);
            tmp[(size_t)(gbl[b] + rank)] =
                ((unsigned)(d & ((1 << BK_SH) - 1)) << 17) | (unsigned)s;
        }
    }
}

// per-bucket CSR emit, deriving per-node offs locally:
// offs[n] = bbase[b] + n0 + excl_scan_local(deg_local+1)
__global__ void __launch_bounds__(256)
k_csr2(const unsigned int* __restrict__ tmp, const int* __restrict__ bbase,
       int N, int Et, int* __restrict__ offs, int* __restrict__ ssrc){
    __shared__ int degl[256];
    __shared__ int rc[256];
    __shared__ int scan[256];
    __shared__ int ofl[256];
    int b = blockIdx.x, tid = threadIdx.x;
    int n0 = b << BK_SH;
    int nloc = min(256, N - n0);
    degl[tid] = 0; rc[tid] = 0;
    __syncthreads();
    int beg = bbase[b], cnt = bbase[b + 1] - beg;
    for (int i = tid; i < cnt; i += 256)
        atomicAdd(&degl[tmp[beg + i] >> 17], 1);
    __syncthreads();
    int v = (tid < nloc) ? degl[tid] + 1 : 0;
    scan[tid] = v;
    __syncthreads();
    for (int off = 1; off < 256; off <<= 1){
        int u = (tid >= off) ? scan[tid - off] : 0;
        __syncthreads();
        scan[tid] += u;
        __syncthreads();
    }
    int base = beg + n0;
    if (tid < nloc){
        int o = base + scan[tid] - v;   // exclusive
        ofl[tid] = o;
        offs[n0 + tid] = o;
        ssrc[o] = n0 + tid;             // self-loop first
    }
    if (b == 0 && tid == 0) offs[N] = Et;
    __syncthreads();
    for (int i = tid; i < cnt; i += 256){
        unsigned int e = tmp[beg + i];
        int dloc = (int)(e >> 17);
        int s = (int)(e & 0x1FFFFu);
        int pos = ofl[dloc] + 1 + atomicAdd(&rc[dloc], 1);
        ssrc[pos] = s;
    }
}

// layer-1 aggregation via rank-2 trick: thread per dst node, gather only x[src]
// (8B/edge, cache-resident). Edge loop unrolled x8 for per-lane MLP.
__global__ void k_agg1s(const float* __restrict__ x, const int* __restrict__ offs,
                        const int* __restrict__ ssrc, const float* __restrict__ cvec,
                        int N, float4* Sa, float4* Sb, float4* Sc){
    int n = blockIdx.x * blockDim.x + threadIdx.x;
    if (n >= N) return;
    float4 cs0 = ((const float4*)cvec)[0];
    float4 cs1 = ((const float4*)cvec)[1];
    float4 cd0 = ((const float4*)cvec)[2];
    float4 cd1 = ((const float4*)cvec)[3];
    float c0[4] = {cs0.x, cs0.y, cs0.z, cs0.w};
    float c1[4] = {cs1.x, cs1.y, cs1.z, cs1.w};
    float2 xn = ((const float2*)x)[n];
    float ad[4] = {xn.x*cd0.x + xn.y*cd1.x, xn.x*cd0.y + xn.y*cd1.y,
                   xn.x*cd0.z + xn.y*cd1.z, xn.x*cd0.w + xn.y*cd1.w};
    float A0[4] = {0,0,0,0}, A1[4] = {0,0,0,0}, D[4] = {0,0,0,0};
    int beg = offs[n], end = offs[n + 1];
    int j = beg;
    for (; j + 8 <= end; j += 8){
        int si[8];
#pragma unroll
        for (int u = 0; u < 8; u++) si[u] = ssrc[j + u];
        float2 xs[8];
#pragma unroll
        for (int u = 0; u < 8; u++) xs[u] = ((const float2*)x)[si[u]];
#pragma unroll
        for (int h = 0; h < HEADS; h++){
#pragma unroll
            for (int u = 0; u < 8; u++){
                float w = __expf(lrelu(xs[u].x * c0[h] + xs[u].y * c1[h] + ad[h]));
                A0[h] += w * xs[u].x;
                A1[h] += w * xs[u].y;
                D[h]  += w;
            }
        }
    }
    if (j + 4 <= end){
        int si[4];
#pragma unroll
        for (int u = 0; u < 4; u++) si[u] = ssrc[j + u];
        float2 xs[4];
#pragma unroll
        for (int u = 0; u < 4; u++) xs[u] = ((const float2*)x)[si[u]];
#pragma unroll
        for (int h = 0; h < HEADS; h++){
#pragma unroll
            for (int u = 0; u < 4; u++){
                float w = __expf(lrelu(xs[u].x * c0[h] + xs[u].y * c1[h] + ad[h]));
                A0[h] += w * xs[u].x;
                A1[h] += w * xs[u].y;
                D[h]  += w;
            }
        }
        j += 4;
    }
    for (; j < end; j++){
        int s = ssrc[j];
        float2 xs = ((const float2*)x)[s];
#pragma unroll
        for (int h = 0; h < HEADS; h++){
            float e = xs.x * c0[h] + xs.y * c1[h] + ad[h];
            float w = __expf(lrelu(e));
            A0[h] += w * xs.x;
            A1[h] += w * xs.y;
            D[h]  += w;
        }
    }
    Sa[n] = make_float4(A0[0], A0[1], A0[2], A0[3]);
    Sb[n] = make_float4(A1[0], A1[1], A1[2], A1[3]);
    Sc[n] = make_float4(D[0],  D[1],  D[2],  D[3]);
}

// Fused layer-2: h1 computed in-register from 12 scalars, GEMM vs W2 with the
// per-wave k-slice of W2 held in a GENUINE register tile (float4 w2v[16],
// static indices; __launch_bounds__(256,2) lifts the VGPR cap that spilled the
// R7 version to scratch  -- VGPR was 52 < 64 needed). hS slices are
// wave-private so phase1->phase2 needs no barrier; only partS does (2/batch).
__global__ void __launch_bounds__(256, 2)
k_l2fused(const float* __restrict__ Saf, const float* __restrict__ Sbf,
          const float* __restrict__ Scf, const float* __restrict__ W1,
          const float* __restrict__ b1, const float* __restrict__ W2,
          const float* __restrict__ as2, const float* __restrict__ ad2,
          int N, __half* __restrict__ xh2, float* __restrict__ asrc,
          float* __restrict__ adst){
    __shared__ float hS[NB][256];        // 16 KB, wave-private 64-col slices
    __shared__ float partS[4][NB][64];   // 16 KB
    int lane = threadIdx.x & 63, w = threadIdx.x >> 6;
    int kk = w * 64 + lane;
    float4 w2v[16];
#pragma unroll
    for (int q = 0; q < 16; q++){
        w2v[q].x = W2[(w * 64 + 4*q    ) * 64 + lane];
        w2v[q].y = W2[(w * 64 + 4*q + 1) * 64 + lane];
        w2v[q].z = W2[(w * 64 + 4*q + 2) * 64 + lane];
        w2v[q].w = W2[(w * 64 + 4*q + 3) * 64 + lane];
    }
    float w10 = W1[kk], w11 = W1[256 + kk], b1k = b1[kk];
    float asw = as2[lane], adw = ad2[lane];

    int nbatches = (N + NB - 1) / NB;
    for (int b = blockIdx.x; b < nbatches; b += gridDim.x){
        int n0 = b * NB;
        // phase 1: expand h rows (each wave fills its own 64-col slice)
#pragma unroll
        for (int m = 0; m < NB; m++){
            int n = n0 + m;
            if (n < N){
                float A0 = Saf[n * 4 + w], A1 = Sbf[n * 4 + w], Dv = Scf[n * 4 + w];
                float u = (A0 * w10 + A1 * w11) / Dv + b1k;
                hS[m][kk] = elu_(u);
            }
        }
        // phase 2: MAC against register W2 tile (uniform b128 broadcast of h)
#pragma unroll
        for (int m = 0; m < NB; m++){
            float acc = 0.f;
            const float4* hp = (const float4*)&hS[m][w * 64];
#pragma unroll
            for (int q = 0; q < 16; q++){
                float4 hv = hp[q];
                acc += hv.x * w2v[q].x + hv.y * w2v[q].y
                     + hv.z * w2v[q].z + hv.w * w2v[q].w;
            }
            partS[w][m][lane] = acc;
        }
        __syncthreads();
        // phase 3: cross-wave reduce + epilogue (wave handles m = w, w+4, ...)
        for (int m = w; m < NB; m += 4){
            int n = n0 + m;
            if (n < N){
                float acc = partS[0][m][lane] + partS[1][m][lane]
                          + partS[2][m][lane] + partS[3][m][lane];
                xh2[(size_t)n * 64 + lane] = __float2half(acc);
                float ps = acc * asw, pd = acc * adw;
#pragma unroll
                for (int off = 32; off; off >>= 1){
                    ps += __shfl_xor(ps, off, 64);
                    pd += __shfl_xor(pd, off, 64);
                }
                if (lane == 0){ asrc[n] = ps; adst[n] = pd; }
            }
        }
        __syncthreads();
    }
}

// layer-2 aggregation fused with global mean pool. f16 rows (128B/edge),
// fp32 logits & accumulation. Edge loop unrolled x4 (R5-proven config).
__global__ void k_agg2p(const __half* __restrict__ xh2, const float* __restrict__ asrc,
                        const float* __restrict__ adst, const int* __restrict__ offs,
                        const int* __restrict__ ssrc, const float* __restrict__ b2,
                        const int* __restrict__ batch, int N,
                        float* sums, int* counts){
    int lane = threadIdx.x & 63, wv = threadIdx.x >> 6;  // 4 waves/block
    int wid = blockIdx.x * 4 + wv;
    int nw = gridDim.x * 4;
    int chunk = (N + nw - 1) / nw;
    int beg = wid * chunk, end = min(beg + chunk, N);
    if (beg >= end) return;
    float b2l = b2[lane];
    float pacc = 0.f; int pcnt = 0; int cur = batch[beg];
    for (int n = beg; n < end; n++){
        float ad = adst[n];
        float acc = 0.f, den = 0.f;
        int e0 = offs[n], e1 = offs[n + 1];
        int j = e0;
        for (; j + 4 <= e1; j += 4){
            int s0 = ssrc[j], s1 = ssrc[j+1], s2 = ssrc[j+2], s3 = ssrc[j+3];
            float a0 = asrc[s0], a1 = asrc[s1], a2 = asrc[s2], a3 = asrc[s3];
            float r0 = __half2float(xh2[(size_t)s0 * 64 + lane]);
            float r1 = __half2float(xh2[(size_t)s1 * 64 + lane]);
            float r2 = __half2float(xh2[(size_t)s2 * 64 + lane]);
            float r3 = __half2float(xh2[(size_t)s3 * 64 + lane]);
            float w0 = __expf(lrelu(a0 + ad));
            float w1 = __expf(lrelu(a1 + ad));
            float w2 = __expf(lrelu(a2 + ad));
            float w3 = __expf(lrelu(a3 + ad));
            acc += w0 * r0 + w1 * r1 + w2 * r2 + w3 * r3;
            den += w0 + w1 + w2 + w3;
        }
        for (; j < e1; j++){
            int s = ssrc[j];
            float wgt = __expf(lrelu(asrc[s] + ad));
            acc += wgt * __half2float(xh2[(size_t)s * 64 + lane]);
            den += wgt;
        }
        float h2v = elu_(acc / den + b2l);
        int g = batch[n];
        if (g != cur){
            atomicAdd(&sums[cur * HID + lane], pacc);
            if (lane == 0) atomicAdd(&counts[cur], pcnt);
            pacc = 0.f; pcnt = 0; cur = g;
        }
        pacc += h2v; pcnt++;
    }
    atomicAdd(&sums[cur * HID + lane], pacc);
    if (lane == 0) atomicAdd(&counts[cur], pcnt);
}

__global__ void k_final(const float* __restrict__ sums, const int* __restrict__ counts,
                        const float* __restrict__ Wl, const float* __restrict__ bl,
                        float* out){
    int t = threadIdx.x;
    if (t >= GR * 2) return;
    int g = t >> 1, task = t & 1;
    float c = (float)max(counts[g], 1);
    float acc = 0.f;
#pragma unroll
    for (int k = 0; k < HID; k++)
        acc += (sums[g * HID + k] / c) * Wl[k * 2 + task];
    out[t] = acc + bl[task];
}

extern "C" void kernel_launch(void* const* d_in, const int* in_sizes, int n_in,
                              void* d_out, int out_size, void* d_ws, size_t ws_size,
                              hipStream_t stream) {
    const float* x    = (const float*)d_in[0];
    const int*   ei   = (const int*)  d_in[1];
    const int*   batch= (const int*)  d_in[2];
    const float* W1   = (const float*)d_in[3];
    const float* as1  = (const float*)d_in[4];
    const float* ad1  = (const float*)d_in[5];
    const float* b1   = (const float*)d_in[6];
    const float* W2   = (const float*)d_in[7];
    const float* as2  = (const float*)d_in[8];
    const float* ad2  = (const float*)d_in[9];
    const float* b2   = (const float*)d_in[10];
    const float* Wl   = (const float*)d_in[11];
    const float* bl   = (const float*)d_in[12];
    float* out = (float*)d_out;

    int N  = in_sizes[0] / 2;
    int E  = in_sizes[1] / 2;
    int Et = E + N;
    const int* srcp = ei;
    const int* dstp = ei + E;

    char* p = (char*)d_ws;
    auto alloc = [&](size_t bytes)->char* {
        char* r = p; p += (bytes + 255) & ~(size_t)255; return r;
    };
    int*    offs   = (int*)   alloc((size_t)(N + 1) * 4);
    int*    bcnt   = (int*)   alloc(NBKT_MAX * 4);
    int*    bbase  = (int*)   alloc((NBKT_MAX + 1) * 4);
    int*    bcursor= (int*)   alloc(NBKT_MAX * 4);
    int*    ssrc   = (int*)   alloc((size_t)Et * 4);
    unsigned int* tmp = (unsigned int*)alloc((size_t)E * 4);
    float*  cvec   = (float*) alloc(16 * 4);
    float4* Sa     = (float4*)alloc((size_t)N * 16);
    float4* Sb     = (float4*)alloc((size_t)N * 16);
    float4* Sc     = (float4*)alloc((size_t)N * 16);
    float*  asrc2  = (float*) alloc((size_t)N * 4);
    float*  adst2  = (float*) alloc((size_t)N * 4);
    float*  sums   = (float*) alloc((size_t)GR * HID * 4);
    int*    counts = (int*)   alloc((size_t)GR * 4);
    __half* xh2    = (__half*)alloc((size_t)N * 64 * 2);

    int nbkt = (N + 255) >> BK_SH;

    k_init <<<16, 256, 0, stream>>>(sums, counts, bcnt, W1, as1, ad1, cvec);
    k_histB<<<256, 256, 0, stream>>>(dstp, E, bcnt);
    k_bscan<<<1, NBKT_MAX, 0, stream>>>(bcnt, bbase, bcursor);
    k_part <<<(E + PART_T - 1) / PART_T, 256, 0, stream>>>(srcp, dstp, E, bcursor, tmp);
    k_csr2 <<<nbkt, 256, 0, stream>>>(tmp, bbase, N, Et, offs, ssrc);

    k_agg1s<<<(N + 255) / 256, 256, 0, stream>>>(x, offs, ssrc, cvec, N, Sa, Sb, Sc);
    k_l2fused<<<2048, 256, 0, stream>>>((const float*)Sa, (const float*)Sb,
                                        (const float*)Sc, W1, b1, W2, as2, ad2,
                                        N, xh2, asrc2, adst2);
    k_agg2p<<<2048, 256, 0, stream>>>(xh2, asrc2, adst2, offs, ssrc, b2,
                                      batch, N, sums, counts);
    k_final<<<1, 128, 0, stream>>>(sums, counts, Wl, bl, out);
}

// Round 9
// 225.594 us; speedup vs baseline: 1.6506x; 1.2223x over previous
//
#include <hip/hip_runtime.h>
#include <hip/hip_fp16.h>
#include <math.h>

#define HID 64
#define HEADS 4
#define GR 64
#define NEG 0.2f
#define NBKT_MAX 512
#define BK_SH 8     // 256 nodes per bucket
#define PART_T 2048 // edges per partition tile
// tmp edge pack: (dst & 255) << 17 | src   -- requires N < 2^17 (N=100000 ok)

typedef _Float16 f16x8 __attribute__((ext_vector_type(8)));
typedef float    f32x4 __attribute__((ext_vector_type(4)));

__device__ __forceinline__ float lrelu(float v){ return v > 0.f ? v : NEG * v; }
__device__ __forceinline__ float elu_(float v){ return v > 0.f ? v : __expf(v) - 1.f; }

// zero pooled sums/counts/bucket-counts; block 0 wave 0 also computes the
// attention-projection constants cvec = [cs0(4), cs1(4), cd0(4), cd1(4)].
// (must run EVERY call: harness does not re-poison ws between timed replays)
__global__ void k_init(float* sums, int* counts, int* bcnt,
                       const float* __restrict__ W1, const float* __restrict__ as1,
                       const float* __restrict__ ad1, float* cvec){
    int i = blockIdx.x * blockDim.x + threadIdx.x;
    if (i < GR * HID) sums[i] = 0.f;
    if (i < GR) counts[i] = 0;
    if (i < NBKT_MAX) bcnt[i] = 0;
    if (blockIdx.x == 0 && threadIdx.x < 64){
        int lane = threadIdx.x;
#pragma unroll
        for (int h = 0; h < HEADS; h++){
            int j = h * HID + lane;
            float s0 = W1[j]       * as1[j];
            float s1 = W1[256 + j] * as1[j];
            float d0 = W1[j]       * ad1[j];
            float d1 = W1[256 + j] * ad1[j];
#pragma unroll
            for (int off = 32; off; off >>= 1){
                s0 += __shfl_xor(s0, off, 64);
                s1 += __shfl_xor(s1, off, 64);
                d0 += __shfl_xor(d0, off, 64);
                d1 += __shfl_xor(d1, off, 64);
            }
            if (lane == 0){
                cvec[h] = s0; cvec[4 + h] = s1; cvec[8 + h] = d0; cvec[12 + h] = d1;
            }
        }
    }
}

// pack W2 into f16 MFMA B-fragments: w2frag[s][c][lane] = 8 halves, where
// elem e -> k = 32s + 4*(lane>>4) + (e&3) + 16*(e>>2), col = 16c + (lane&15).
// (A uses the SAME (group,elem)->k bijection, so the MFMA sum over k is
// correct for ANY true hardware k-map as long as A/B share lane&15 free idx.)
__global__ void k_w2frag(const float* __restrict__ W2, uint4* __restrict__ w2frag){
    int t = blockIdx.x * blockDim.x + threadIdx.x;  // 2048 threads
    if (t >= 2048) return;
    int lane = t & 63, c = (t >> 6) & 3, s = t >> 8;
    union { uint4 u; _Float16 h[8]; } o;
#pragma unroll
    for (int e = 0; e < 8; e++){
        int k = 32 * s + 4 * (lane >> 4) + (e & 3) + 16 * (e >> 2);
        int col = 16 * c + (lane & 15);
        o.h[e] = (_Float16)W2[k * 64 + col];
    }
    w2frag[t] = o.u;
}

// bucket-level histogram only (per-node degrees derived in k_csr2)
__global__ void k_histB(const int* __restrict__ dst, int E, int* bcnt){
    __shared__ int bh[NBKT_MAX];
    for (int b = threadIdx.x; b < NBKT_MAX; b += blockDim.x) bh[b] = 0;
    __syncthreads();
    int stride = gridDim.x * blockDim.x;
    for (int i = blockIdx.x * blockDim.x + threadIdx.x; i < E; i += stride)
        atomicAdd(&bh[dst[i] >> BK_SH], 1);
    __syncthreads();
    for (int b = threadIdx.x; b < NBKT_MAX; b += blockDim.x)
        if (bh[b]) atomicAdd(&bcnt[b], bh[b]);
}

// exclusive scan of bucket counts -> bucket bases + partition cursors.
__global__ void k_bscan(const int* __restrict__ bcnt, int* bbase, int* bcursor){
    __shared__ int sh[NBKT_MAX];
    int t = threadIdx.x;     // 512 threads
    int v = bcnt[t];
    sh[t] = v;
    __syncthreads();
    for (int off = 1; off < NBKT_MAX; off <<= 1){
        int u = (t >= off) ? sh[t - off] : 0;
        __syncthreads();
        sh[t] += u;
        __syncthreads();
    }
    bbase[t] = sh[t] - v;
    bcursor[t] = sh[t] - v;
    if (t == NBKT_MAX - 1) bbase[NBKT_MAX] = sh[t];
}

// staged partition: per-tile LDS bucket count -> one global reserve per
// (block,bucket) -> scatter packed u32 (dloc<<17|src) into block-private runs.
__global__ void __launch_bounds__(256)
k_part(const int* __restrict__ src, const int* __restrict__ dst, int E,
       int* bcursor, unsigned int* __restrict__ tmp){
    __shared__ int bh[NBKT_MAX];
    __shared__ int gbl[NBKT_MAX];
    int tid = threadIdx.x;
    int base = blockIdx.x * PART_T;
    for (int b = tid; b < NBKT_MAX; b += 256) bh[b] = 0;
    __syncthreads();
#pragma unroll
    for (int r = 0; r < PART_T / 256; r++){
        int i = base + r * 256 + tid;
        if (i < E) atomicAdd(&bh[dst[i] >> BK_SH], 1);
    }
    __syncthreads();
    for (int b = tid; b < NBKT_MAX; b += 256){
        int c = bh[b];
        gbl[b] = c ? atomicAdd(&bcursor[b], c) : 0;
        bh[b] = 0;
    }
    __syncthreads();
#pragma unroll
    for (int r = 0; r < PART_T / 256; r++){
        int i = base + r * 256 + tid;
        if (i < E){
            int s = src[i], d = dst[i];
            int b = d >> BK_SH;
            int rank = atomicAdd(&bh[b], 1);
            tmp[(size_t)(gbl[b] + rank)] =
                ((unsigned)(d & ((1 << BK_SH) - 1)) << 17) | (unsigned)s;
        }
    }
}

// per-bucket CSR emit, deriving per-node offs locally:
// offs[n] = bbase[b] + n0 + excl_scan_local(deg_local+1)
__global__ void __launch_bounds__(256)
k_csr2(const unsigned int* __restrict__ tmp, const int* __restrict__ bbase,
       int N, int Et, int* __restrict__ offs, int* __restrict__ ssrc){
    __shared__ int degl[256];
    __shared__ int rc[256];
    __shared__ int scan[256];
    __shared__ int ofl[256];
    int b = blockIdx.x, tid = threadIdx.x;
    int n0 = b << BK_SH;
    int nloc = min(256, N - n0);
    degl[tid] = 0; rc[tid] = 0;
    __syncthreads();
    int beg = bbase[b], cnt = bbase[b + 1] - beg;
    for (int i = tid; i < cnt; i += 256)
        atomicAdd(&degl[tmp[beg + i] >> 17], 1);
    __syncthreads();
    int v = (tid < nloc) ? degl[tid] + 1 : 0;
    scan[tid] = v;
    __syncthreads();
    for (int off = 1; off < 256; off <<= 1){
        int u = (tid >= off) ? scan[tid - off] : 0;
        __syncthreads();
        scan[tid] += u;
        __syncthreads();
    }
    int base = beg + n0;
    if (tid < nloc){
        int o = base + scan[tid] - v;   // exclusive
        ofl[tid] = o;
        offs[n0 + tid] = o;
        ssrc[o] = n0 + tid;             // self-loop first
    }
    if (b == 0 && tid == 0) offs[N] = Et;
    __syncthreads();
    for (int i = tid; i < cnt; i += 256){
        unsigned int e = tmp[beg + i];
        int dloc = (int)(e >> 17);
        int s = (int)(e & 0x1FFFFu);
        int pos = ofl[dloc] + 1 + atomicAdd(&rc[dloc], 1);
        ssrc[pos] = s;
    }
}

// layer-1 aggregation via rank-2 trick: thread per dst node, gather only x[src]
// (8B/edge, cache-resident). Edge loop unrolled x8 for per-lane MLP.
__global__ void k_agg1s(const float* __restrict__ x, const int* __restrict__ offs,
                        const int* __restrict__ ssrc, const float* __restrict__ cvec,
                        int N, float4* Sa, float4* Sb, float4* Sc){
    int n = blockIdx.x * blockDim.x + threadIdx.x;
    if (n >= N) return;
    float4 cs0 = ((const float4*)cvec)[0];
    float4 cs1 = ((const float4*)cvec)[1];
    float4 cd0 = ((const float4*)cvec)[2];
    float4 cd1 = ((const float4*)cvec)[3];
    float c0[4] = {cs0.x, cs0.y, cs0.z, cs0.w};
    float c1[4] = {cs1.x, cs1.y, cs1.z, cs1.w};
    float2 xn = ((const float2*)x)[n];
    float ad[4] = {xn.x*cd0.x + xn.y*cd1.x, xn.x*cd0.y + xn.y*cd1.y,
                   xn.x*cd0.z + xn.y*cd1.z, xn.x*cd0.w + xn.y*cd1.w};
    float A0[4] = {0,0,0,0}, A1[4] = {0,0,0,0}, D[4] = {0,0,0,0};
    int beg = offs[n], end = offs[n + 1];
    int j = beg;
    for (; j + 8 <= end; j += 8){
        int si[8];
#pragma unroll
        for (int u = 0; u < 8; u++) si[u] = ssrc[j + u];
        float2 xs[8];
#pragma unroll
        for (int u = 0; u < 8; u++) xs[u] = ((const float2*)x)[si[u]];
#pragma unroll
        for (int h = 0; h < HEADS; h++){
#pragma unroll
            for (int u = 0; u < 8; u++){
                float w = __expf(lrelu(xs[u].x * c0[h] + xs[u].y * c1[h] + ad[h]));
                A0[h] += w * xs[u].x;
                A1[h] += w * xs[u].y;
                D[h]  += w;
            }
        }
    }
    if (j + 4 <= end){
        int si[4];
#pragma unroll
        for (int u = 0; u < 4; u++) si[u] = ssrc[j + u];
        float2 xs[4];
#pragma unroll
        for (int u = 0; u < 4; u++) xs[u] = ((const float2*)x)[si[u]];
#pragma unroll
        for (int h = 0; h < HEADS; h++){
#pragma unroll
            for (int u = 0; u < 4; u++){
                float w = __expf(lrelu(xs[u].x * c0[h] + xs[u].y * c1[h] + ad[h]));
                A0[h] += w * xs[u].x;
                A1[h] += w * xs[u].y;
                D[h]  += w;
            }
        }
        j += 4;
    }
    for (; j < end; j++){
        int s = ssrc[j];
        float2 xs = ((const float2*)x)[s];
#pragma unroll
        for (int h = 0; h < HEADS; h++){
            float e = xs.x * c0[h] + xs.y * c1[h] + ad[h];
            float w = __expf(lrelu(e));
            A0[h] += w * xs.x;
            A1[h] += w * xs.y;
            D[h]  += w;
        }
    }
    Sa[n] = make_float4(A0[0], A0[1], A0[2], A0[3]);
    Sb[n] = make_float4(A1[0], A1[1], A1[2], A1[3]);
    Sc[n] = make_float4(D[0],  D[1],  D[2],  D[3]);
}

// expand h1 to f16 [N][256] row-major, coalesced. thread = (node, 4 k's).
// h1[n][k] = elu((Sa[n][k>>6]*W1[0][k] + Sb[n][k>>6]*W1[1][k])/Sc[n][k>>6] + b1[k])
__global__ void __launch_bounds__(256)
k_h1f16(const float* __restrict__ Saf, const float* __restrict__ Sbf,
        const float* __restrict__ Scf, const float* __restrict__ W1,
        const float* __restrict__ b1, int N, _Float16* __restrict__ h1){
    int tid = blockIdx.x * blockDim.x + threadIdx.x;
    int n = tid >> 6, lane = tid & 63;
    if (n >= N) return;
    int k0 = lane * 4;
    int head = lane >> 4;          // k0>>6
    float a0 = Saf[n * 4 + head];
    float a1 = Sbf[n * 4 + head];
    float rd = 1.0f / Scf[n * 4 + head];
    float4 w0 = *(const float4*)(W1 + k0);
    float4 w1 = *(const float4*)(W1 + 256 + k0);
    float4 bv = *(const float4*)(b1 + k0);
    union { uint2 u; _Float16 h[4]; } o;
    o.h[0] = (_Float16)elu_((a0 * w0.x + a1 * w1.x) * rd + bv.x);
    o.h[1] = (_Float16)elu_((a0 * w0.y + a1 * w1.y) * rd + bv.y);
    o.h[2] = (_Float16)elu_((a0 * w0.z + a1 * w1.z) * rd + bv.z);
    o.h[3] = (_Float16)elu_((a0 * w0.w + a1 * w1.w) * rd + bv.w);
    ((uint2*)h1)[(size_t)n * 64 + lane] = o.u;
}

// MFMA layer-2 GEMM: per wave, 16-node tile x 64 cols, K=256 in 8 steps of 32.
// A = h1 f16 (2x 8B loads per k-step), B = w2frag via LDS (4x b128 per k-step),
// D rows = 4*(lane>>4)+reg, cols = 16c + (lane&15)  [C/D layout HW-verified].
// Epilogue: xh2 f16 + attention dots asrc/adst (fp32).
__global__ void __launch_bounds__(256)
k_mfma(const _Float16* __restrict__ h1, const uint4* __restrict__ w2frag,
       const float* __restrict__ as2, const float* __restrict__ ad2,
       int N, __half* __restrict__ xh2, float* __restrict__ asrc,
       float* __restrict__ adst){
    __shared__ uint4 w2s[2048];    // 32 KB: B fragments [s][c][lane]
    int tid = threadIdx.x;
    for (int i = tid; i < 2048; i += 256) w2s[i] = w2frag[i];
    __syncthreads();

    int lane = tid & 63, wv = tid >> 6;
    int r = lane & 15, g = lane >> 4;
    float asw0 = as2[r], asw1 = as2[16 + r], asw2 = as2[32 + r], asw3 = as2[48 + r];
    float adw0 = ad2[r], adw1 = ad2[16 + r], adw2 = ad2[32 + r], adw3 = ad2[48 + r];

    int ntiles = (N + 15) >> 4;
    for (int t = blockIdx.x * 4 + wv; t < ntiles; t += gridDim.x * 4){
        int base = t << 4;
        int nodeA = min(base + r, N - 1);
        const _Float16* ap = h1 + (size_t)nodeA * 256 + 4 * g;
        f32x4 ac0 = {0.f,0.f,0.f,0.f}, ac1 = {0.f,0.f,0.f,0.f};
        f32x4 ac2 = {0.f,0.f,0.f,0.f}, ac3 = {0.f,0.f,0.f,0.f};
#pragma unroll
        for (int s = 0; s < 8; s++){
            uint2 lo = *(const uint2*)(ap + 32 * s);
            uint2 hi = *(const uint2*)(ap + 32 * s + 16);
            union { uint4 u; f16x8 f; } a;
            a.u = make_uint4(lo.x, lo.y, hi.x, hi.y);
            union { uint4 u; f16x8 f; } b0, b1, b2, b3;
            b0.u = w2s[(s * 4 + 0) * 64 + lane];
            b1.u = w2s[(s * 4 + 1) * 64 + lane];
            b2.u = w2s[(s * 4 + 2) * 64 + lane];
            b3.u = w2s[(s * 4 + 3) * 64 + lane];
            ac0 = __builtin_amdgcn_mfma_f32_16x16x32_f16(a.f, b0.f, ac0, 0, 0, 0);
            ac1 = __builtin_amdgcn_mfma_f32_16x16x32_f16(a.f, b1.f, ac1, 0, 0, 0);
            ac2 = __builtin_amdgcn_mfma_f32_16x16x32_f16(a.f, b2.f, ac2, 0, 0, 0);
            ac3 = __builtin_amdgcn_mfma_f32_16x16x32_f16(a.f, b3.f, ac3, 0, 0, 0);
        }
        // epilogue: stores + attention dots
        float ps0 = 0.f, ps1 = 0.f, ps2 = 0.f, ps3 = 0.f;
        float pd0 = 0.f, pd1 = 0.f, pd2 = 0.f, pd3 = 0.f;
#pragma unroll
        for (int reg = 0; reg < 4; reg++){
            int node = base + 4 * g + reg;
            if (node < N){
                size_t rowb = (size_t)node * 64;
                xh2[rowb +      r] = __float2half(ac0[reg]);
                xh2[rowb + 16 + r] = __float2half(ac1[reg]);
                xh2[rowb + 32 + r] = __float2half(ac2[reg]);
                xh2[rowb + 48 + r] = __float2half(ac3[reg]);
            }
            float ps = ac0[reg]*asw0 + ac1[reg]*asw1 + ac2[reg]*asw2 + ac3[reg]*asw3;
            float pd = ac0[reg]*adw0 + ac1[reg]*adw1 + ac2[reg]*adw2 + ac3[reg]*adw3;
            if (reg == 0){ ps0 = ps; pd0 = pd; }
            else if (reg == 1){ ps1 = ps; pd1 = pd; }
            else if (reg == 2){ ps2 = ps; pd2 = pd; }
            else { ps3 = ps; pd3 = pd; }
        }
#pragma unroll
        for (int m = 1; m < 16; m <<= 1){
            ps0 += __shfl_xor(ps0, m, 64); pd0 += __shfl_xor(pd0, m, 64);
            ps1 += __shfl_xor(ps1, m, 64); pd1 += __shfl_xor(pd1, m, 64);
            ps2 += __shfl_xor(ps2, m, 64); pd2 += __shfl_xor(pd2, m, 64);
            ps3 += __shfl_xor(ps3, m, 64); pd3 += __shfl_xor(pd3, m, 64);
        }
        if (r == 0){
            int nb = base + 4 * g;
            if (nb     < N){ asrc[nb    ] = ps0; adst[nb    ] = pd0; }
            if (nb + 1 < N){ asrc[nb + 1] = ps1; adst[nb + 1] = pd1; }
            if (nb + 2 < N){ asrc[nb + 2] = ps2; adst[nb + 2] = pd2; }
            if (nb + 3 < N){ asrc[nb + 3] = ps3; adst[nb + 3] = pd3; }
        }
    }
}

// layer-2 aggregation fused with global mean pool. f16 rows (128B/edge),
// fp32 logits & accumulation. Edge loop unrolled x4 (R5-proven config).
__global__ void k_agg2p(const __half* __restrict__ xh2, const float* __restrict__ asrc,
                        const float* __restrict__ adst, const int* __restrict__ offs,
                        const int* __restrict__ ssrc, const float* __restrict__ b2,
                        const int* __restrict__ batch, int N,
                        float* sums, int* counts){
    int lane = threadIdx.x & 63, wv = threadIdx.x >> 6;  // 4 waves/block
    int wid = blockIdx.x * 4 + wv;
    int nw = gridDim.x * 4;
    int chunk = (N + nw - 1) / nw;
    int beg = wid * chunk, end = min(beg + chunk, N);
    if (beg >= end) return;
    float b2l = b2[lane];
    float pacc = 0.f; int pcnt = 0; int cur = batch[beg];
    for (int n = beg; n < end; n++){
        float ad = adst[n];
        float acc = 0.f, den = 0.f;
        int e0 = offs[n], e1 = offs[n + 1];
        int j = e0;
        for (; j + 4 <= e1; j += 4){
            int s0 = ssrc[j], s1 = ssrc[j+1], s2 = ssrc[j+2], s3 = ssrc[j+3];
            float a0 = asrc[s0], a1 = asrc[s1], a2 = asrc[s2], a3 = asrc[s3];
            float r0 = __half2float(xh2[(size_t)s0 * 64 + lane]);
            float r1 = __half2float(xh2[(size_t)s1 * 64 + lane]);
            float r2 = __half2float(xh2[(size_t)s2 * 64 + lane]);
            float r3 = __half2float(xh2[(size_t)s3 * 64 + lane]);
            float w0 = __expf(lrelu(a0 + ad));
            float w1 = __expf(lrelu(a1 + ad));
            float w2 = __expf(lrelu(a2 + ad));
            float w3 = __expf(lrelu(a3 + ad));
            acc += w0 * r0 + w1 * r1 + w2 * r2 + w3 * r3;
            den += w0 + w1 + w2 + w3;
        }
        for (; j < e1; j++){
            int s = ssrc[j];
            float wgt = __expf(lrelu(asrc[s] + ad));
            acc += wgt * __half2float(xh2[(size_t)s * 64 + lane]);
            den += wgt;
        }
        float h2v = elu_(acc / den + b2l);
        int g = batch[n];
        if (g != cur){
            atomicAdd(&sums[cur * HID + lane], pacc);
            if (lane == 0) atomicAdd(&counts[cur], pcnt);
            pacc = 0.f; pcnt = 0; cur = g;
        }
        pacc += h2v; pcnt++;
    }
    atomicAdd(&sums[cur * HID + lane], pacc);
    if (lane == 0) atomicAdd(&counts[cur], pcnt);
}

__global__ void k_final(const float* __restrict__ sums, const int* __restrict__ counts,
                        const float* __restrict__ Wl, const float* __restrict__ bl,
                        float* out){
    int t = threadIdx.x;
    if (t >= GR * 2) return;
    int g = t >> 1, task = t & 1;
    float c = (float)max(counts[g], 1);
    float acc = 0.f;
#pragma unroll
    for (int k = 0; k < HID; k++)
        acc += (sums[g * HID + k] / c) * Wl[k * 2 + task];
    out[t] = acc + bl[task];
}

extern "C" void kernel_launch(void* const* d_in, const int* in_sizes, int n_in,
                              void* d_out, int out_size, void* d_ws, size_t ws_size,
                              hipStream_t stream) {
    const float* x    = (const float*)d_in[0];
    const int*   ei   = (const int*)  d_in[1];
    const int*   batch= (const int*)  d_in[2];
    const float* W1   = (const float*)d_in[3];
    const float* as1  = (const float*)d_in[4];
    const float* ad1  = (const float*)d_in[5];
    const float* b1   = (const float*)d_in[6];
    const float* W2   = (const float*)d_in[7];
    const float* as2  = (const float*)d_in[8];
    const float* ad2  = (const float*)d_in[9];
    const float* b2   = (const float*)d_in[10];
    const float* Wl   = (const float*)d_in[11];
    const float* bl   = (const float*)d_in[12];
    float* out = (float*)d_out;

    int N  = in_sizes[0] / 2;
    int E  = in_sizes[1] / 2;
    int Et = E + N;
    const int* srcp = ei;
    const int* dstp = ei + E;

    char* p = (char*)d_ws;
    auto alloc = [&](size_t bytes)->char* {
        char* r = p; p += (bytes + 255) & ~(size_t)255; return r;
    };
    int*    offs   = (int*)   alloc((size_t)(N + 1) * 4);
    int*    bcnt   = (int*)   alloc(NBKT_MAX * 4);
    int*    bbase  = (int*)   alloc((NBKT_MAX + 1) * 4);
    int*    bcursor= (int*)   alloc(NBKT_MAX * 4);
    int*    ssrc   = (int*)   alloc((size_t)Et * 4);
    unsigned int* tmp = (unsigned int*)alloc((size_t)E * 4);
    float*  cvec   = (float*) alloc(16 * 4);
    float4* Sa     = (float4*)alloc((size_t)N * 16);
    float4* Sb     = (float4*)alloc((size_t)N * 16);
    float4* Sc     = (float4*)alloc((size_t)N * 16);
    float*  asrc2  = (float*) alloc((size_t)N * 4);
    float*  adst2  = (float*) alloc((size_t)N * 4);
    float*  sums   = (float*) alloc((size_t)GR * HID * 4);
    int*    counts = (int*)   alloc((size_t)GR * 4);
    uint4*  w2frag = (uint4*) alloc(2048 * 16);
    _Float16* h1f  = (_Float16*)alloc((size_t)N * 256 * 2);
    __half* xh2    = (__half*)alloc((size_t)N * 64 * 2);

    int nbkt = (N + 255) >> BK_SH;

    k_init  <<<16, 256, 0, stream>>>(sums, counts, bcnt, W1, as1, ad1, cvec);
    k_w2frag<<<8, 256, 0, stream>>>(W2, w2frag);
    k_histB <<<256, 256, 0, stream>>>(dstp, E, bcnt);
    k_bscan <<<1, NBKT_MAX, 0, stream>>>(bcnt, bbase, bcursor);
    k_part  <<<(E + PART_T - 1) / PART_T, 256, 0, stream>>>(srcp, dstp, E, bcursor, tmp);
    k_csr2  <<<nbkt, 256, 0, stream>>>(tmp, bbase, N, Et, offs, ssrc);

    k_agg1s <<<(N + 255) / 256, 256, 0, stream>>>(x, offs, ssrc, cvec, N, Sa, Sb, Sc);
    k_h1f16 <<<(N * 64 + 255) / 256, 256, 0, stream>>>((const float*)Sa, (const float*)Sb,
                                                       (const float*)Sc, W1, b1, N, h1f);
    k_mfma  <<<1024, 256, 0, stream>>>(h1f, w2frag, as2, ad2, N, xh2, asrc2, adst2);
    k_agg2p <<<2048, 256, 0, stream>>>(xh2, asrc2, adst2, offs, ssrc, b2,
                                       batch, N, sums, counts);
    k_final <<<1, 128, 0, stream>>>(sums, counts, Wl, bl, out);
}

// Round 10
// 213.639 us; speedup vs baseline: 1.7430x; 1.0560x over previous
//
#include <hip/hip_runtime.h>
#include <hip/hip_fp16.h>
#include <math.h>

#define HID 64
#define HEADS 4
#define GR 64
#define NEG 0.2f
#define NBKT_MAX 512
#define BK_SH 8     // 256 nodes per bucket
#define PART_T 2048 // edges per partition tile
// tmp edge pack: (dst & 255) << 17 | src   -- requires N < 2^17 (N=100000 ok)

typedef _Float16 f16x8 __attribute__((ext_vector_type(8)));
typedef float    f32x4 __attribute__((ext_vector_type(4)));

__device__ __forceinline__ float lrelu(float v){ return v > 0.f ? v : NEG * v; }
__device__ __forceinline__ float elu_(float v){ return v > 0.f ? v : __expf(v) - 1.f; }

// zero pooled sums/counts/bucket-counts; block 0 wave 0 also computes the
// attention-projection constants cvec = [cs0(4), cs1(4), cd0(4), cd1(4)].
// (must run EVERY call: harness does not re-poison ws between timed replays)
__global__ void k_init(float* sums, int* counts, int* bcnt,
                       const float* __restrict__ W1, const float* __restrict__ as1,
                       const float* __restrict__ ad1, float* cvec){
    int i = blockIdx.x * blockDim.x + threadIdx.x;
    if (i < GR * HID) sums[i] = 0.f;
    if (i < GR) counts[i] = 0;
    if (i < NBKT_MAX) bcnt[i] = 0;
    if (blockIdx.x == 0 && threadIdx.x < 64){
        int lane = threadIdx.x;
#pragma unroll
        for (int h = 0; h < HEADS; h++){
            int j = h * HID + lane;
            float s0 = W1[j]       * as1[j];
            float s1 = W1[256 + j] * as1[j];
            float d0 = W1[j]       * ad1[j];
            float d1 = W1[256 + j] * ad1[j];
#pragma unroll
            for (int off = 32; off; off >>= 1){
                s0 += __shfl_xor(s0, off, 64);
                s1 += __shfl_xor(s1, off, 64);
                d0 += __shfl_xor(d0, off, 64);
                d1 += __shfl_xor(d1, off, 64);
            }
            if (lane == 0){
                cvec[h] = s0; cvec[4 + h] = s1; cvec[8 + h] = d0; cvec[12 + h] = d1;
            }
        }
    }
}

// pack W2 into f16 MFMA B-fragments: w2frag[s][c][lane] = 8 halves, where
// elem e -> k = 32s + 4*(lane>>4) + (e&3) + 16*(e>>2), col = 16c + (lane&15).
__global__ void k_w2frag(const float* __restrict__ W2, uint4* __restrict__ w2frag){
    int t = blockIdx.x * blockDim.x + threadIdx.x;  // 2048 threads
    if (t >= 2048) return;
    int lane = t & 63, c = (t >> 6) & 3, s = t >> 8;
    union { uint4 u; _Float16 h[8]; } o;
#pragma unroll
    for (int e = 0; e < 8; e++){
        int k = 32 * s + 4 * (lane >> 4) + (e & 3) + 16 * (e >> 2);
        int col = 16 * c + (lane & 15);
        o.h[e] = (_Float16)W2[k * 64 + col];
    }
    w2frag[t] = o.u;
}

// bucket-level histogram only (per-node degrees derived in k_csr2)
__global__ void k_histB(const int* __restrict__ dst, int E, int* bcnt){
    __shared__ int bh[NBKT_MAX];
    for (int b = threadIdx.x; b < NBKT_MAX; b += blockDim.x) bh[b] = 0;
    __syncthreads();
    int stride = gridDim.x * blockDim.x;
    for (int i = blockIdx.x * blockDim.x + threadIdx.x; i < E; i += stride)
        atomicAdd(&bh[dst[i] >> BK_SH], 1);
    __syncthreads();
    for (int b = threadIdx.x; b < NBKT_MAX; b += blockDim.x)
        if (bh[b]) atomicAdd(&bcnt[b], bh[b]);
}

// exclusive scan of bucket counts -> bucket bases + partition cursors.
__global__ void k_bscan(const int* __restrict__ bcnt, int* bbase, int* bcursor){
    __shared__ int sh[NBKT_MAX];
    int t = threadIdx.x;     // 512 threads
    int v = bcnt[t];
    sh[t] = v;
    __syncthreads();
    for (int off = 1; off < NBKT_MAX; off <<= 1){
        int u = (t >= off) ? sh[t - off] : 0;
        __syncthreads();
        sh[t] += u;
        __syncthreads();
    }
    bbase[t] = sh[t] - v;
    bcursor[t] = sh[t] - v;
    if (t == NBKT_MAX - 1) bbase[NBKT_MAX] = sh[t];
}

// staged partition: per-tile LDS bucket count -> one global reserve per
// (block,bucket) -> scatter packed u32 (dloc<<17|src) into block-private runs.
__global__ void __launch_bounds__(256)
k_part(const int* __restrict__ src, const int* __restrict__ dst, int E,
       int* bcursor, unsigned int* __restrict__ tmp){
    __shared__ int bh[NBKT_MAX];
    __shared__ int gbl[NBKT_MAX];
    int tid = threadIdx.x;
    int base = blockIdx.x * PART_T;
    for (int b = tid; b < NBKT_MAX; b += 256) bh[b] = 0;
    __syncthreads();
#pragma unroll
    for (int r = 0; r < PART_T / 256; r++){
        int i = base + r * 256 + tid;
        if (i < E) atomicAdd(&bh[dst[i] >> BK_SH], 1);
    }
    __syncthreads();
    for (int b = tid; b < NBKT_MAX; b += 256){
        int c = bh[b];
        gbl[b] = c ? atomicAdd(&bcursor[b], c) : 0;
        bh[b] = 0;
    }
    __syncthreads();
#pragma unroll
    for (int r = 0; r < PART_T / 256; r++){
        int i = base + r * 256 + tid;
        if (i < E){
            int s = src[i], d = dst[i];
            int b = d >> BK_SH;
            int rank = atomicAdd(&bh[b], 1);
            tmp[(size_t)(gbl[b] + rank)] =
                ((unsigned)(d & ((1 << BK_SH) - 1)) << 17) | (unsigned)s;
        }
    }
}

// per-bucket CSR emit, deriving per-node offs locally:
// offs[n] = bbase[b] + n0 + excl_scan_local(deg_local+1)
__global__ void __launch_bounds__(256)
k_csr2(const unsigned int* __restrict__ tmp, const int* __restrict__ bbase,
       int N, int Et, int* __restrict__ offs, int* __restrict__ ssrc){
    __shared__ int degl[256];
    __shared__ int rc[256];
    __shared__ int scan[256];
    __shared__ int ofl[256];
    int b = blockIdx.x, tid = threadIdx.x;
    int n0 = b << BK_SH;
    int nloc = min(256, N - n0);
    degl[tid] = 0; rc[tid] = 0;
    __syncthreads();
    int beg = bbase[b], cnt = bbase[b + 1] - beg;
    for (int i = tid; i < cnt; i += 256)
        atomicAdd(&degl[tmp[beg + i] >> 17], 1);
    __syncthreads();
    int v = (tid < nloc) ? degl[tid] + 1 : 0;
    scan[tid] = v;
    __syncthreads();
    for (int off = 1; off < 256; off <<= 1){
        int u = (tid >= off) ? scan[tid - off] : 0;
        __syncthreads();
        scan[tid] += u;
        __syncthreads();
    }
    int base = beg + n0;
    if (tid < nloc){
        int o = base + scan[tid] - v;   // exclusive
        ofl[tid] = o;
        offs[n0 + tid] = o;
        ssrc[o] = n0 + tid;             // self-loop first
    }
    if (b == 0 && tid == 0) offs[N] = Et;
    __syncthreads();
    for (int i = tid; i < cnt; i += 256){
        unsigned int e = tmp[beg + i];
        int dloc = (int)(e >> 17);
        int s = (int)(e & 0x1FFFFu);
        int pos = ofl[dloc] + 1 + atomicAdd(&rc[dloc], 1);
        ssrc[pos] = s;
    }
}

// layer-1 aggregation via rank-2 trick: thread per dst node, gather only x[src]
// (8B/edge, cache-resident). Edge loop unrolled x8 for per-lane MLP.
__global__ void k_agg1s(const float* __restrict__ x, const int* __restrict__ offs,
                        const int* __restrict__ ssrc, const float* __restrict__ cvec,
                        int N, float4* Sa, float4* Sb, float4* Sc){
    int n = blockIdx.x * blockDim.x + threadIdx.x;
    if (n >= N) return;
    float4 cs0 = ((const float4*)cvec)[0];
    float4 cs1 = ((const float4*)cvec)[1];
    float4 cd0 = ((const float4*)cvec)[2];
    float4 cd1 = ((const float4*)cvec)[3];
    float c0[4] = {cs0.x, cs0.y, cs0.z, cs0.w};
    float c1[4] = {cs1.x, cs1.y, cs1.z, cs1.w};
    float2 xn = ((const float2*)x)[n];
    float ad[4] = {xn.x*cd0.x + xn.y*cd1.x, xn.x*cd0.y + xn.y*cd1.y,
                   xn.x*cd0.z + xn.y*cd1.z, xn.x*cd0.w + xn.y*cd1.w};
    float A0[4] = {0,0,0,0}, A1[4] = {0,0,0,0}, D[4] = {0,0,0,0};
    int beg = offs[n], end = offs[n + 1];
    int j = beg;
    for (; j + 8 <= end; j += 8){
        int si[8];
#pragma unroll
        for (int u = 0; u < 8; u++) si[u] = ssrc[j + u];
        float2 xs[8];
#pragma unroll
        for (int u = 0; u < 8; u++) xs[u] = ((const float2*)x)[si[u]];
#pragma unroll
        for (int h = 0; h < HEADS; h++){
#pragma unroll
            for (int u = 0; u < 8; u++){
                float w = __expf(lrelu(xs[u].x * c0[h] + xs[u].y * c1[h] + ad[h]));
                A0[h] += w * xs[u].x;
                A1[h] += w * xs[u].y;
                D[h]  += w;
            }
        }
    }
    if (j + 4 <= end){
        int si[4];
#pragma unroll
        for (int u = 0; u < 4; u++) si[u] = ssrc[j + u];
        float2 xs[4];
#pragma unroll
        for (int u = 0; u < 4; u++) xs[u] = ((const float2*)x)[si[u]];
#pragma unroll
        for (int h = 0; h < HEADS; h++){
#pragma unroll
            for (int u = 0; u < 4; u++){
                float w = __expf(lrelu(xs[u].x * c0[h] + xs[u].y * c1[h] + ad[h]));
                A0[h] += w * xs[u].x;
                A1[h] += w * xs[u].y;
                D[h]  += w;
            }
        }
        j += 4;
    }
    for (; j < end; j++){
        int s = ssrc[j];
        float2 xs = ((const float2*)x)[s];
#pragma unroll
        for (int h = 0; h < HEADS; h++){
            float e = xs.x * c0[h] + xs.y * c1[h] + ad[h];
            float w = __expf(lrelu(e));
            A0[h] += w * xs.x;
            A1[h] += w * xs.y;
            D[h]  += w;
        }
    }
    Sa[n] = make_float4(A0[0], A0[1], A0[2], A0[3]);
    Sb[n] = make_float4(A1[0], A1[1], A1[2], A1[3]);
    Sc[n] = make_float4(D[0],  D[1],  D[2],  D[3]);
}

// expand h1 to f16 [N][256] row-major, coalesced. thread = (node, 4 k's).
__global__ void __launch_bounds__(256)
k_h1f16(const float* __restrict__ Saf, const float* __restrict__ Sbf,
        const float* __restrict__ Scf, const float* __restrict__ W1,
        const float* __restrict__ b1, int N, _Float16* __restrict__ h1){
    int tid = blockIdx.x * blockDim.x + threadIdx.x;
    int n = tid >> 6, lane = tid & 63;
    if (n >= N) return;
    int k0 = lane * 4;
    int head = lane >> 4;          // k0>>6
    float a0 = Saf[n * 4 + head];
    float a1 = Sbf[n * 4 + head];
    float rd = 1.0f / Scf[n * 4 + head];
    float4 w0 = *(const float4*)(W1 + k0);
    float4 w1 = *(const float4*)(W1 + 256 + k0);
    float4 bv = *(const float4*)(b1 + k0);
    union { uint2 u; _Float16 h[4]; } o;
    o.h[0] = (_Float16)elu_((a0 * w0.x + a1 * w1.x) * rd + bv.x);
    o.h[1] = (_Float16)elu_((a0 * w0.y + a1 * w1.y) * rd + bv.y);
    o.h[2] = (_Float16)elu_((a0 * w0.z + a1 * w1.z) * rd + bv.z);
    o.h[3] = (_Float16)elu_((a0 * w0.w + a1 * w1.w) * rd + bv.w);
    ((uint2*)h1)[(size_t)n * 64 + lane] = o.u;
}

// MFMA layer-2 GEMM: per wave, 16-node tile x 64 cols, K=256 in 8 steps of 32.
__global__ void __launch_bounds__(256)
k_mfma(const _Float16* __restrict__ h1, const uint4* __restrict__ w2frag,
       const float* __restrict__ as2, const float* __restrict__ ad2,
       int N, __half* __restrict__ xh2, float* __restrict__ asrc,
       float* __restrict__ adst){
    __shared__ uint4 w2s[2048];    // 32 KB: B fragments [s][c][lane]
    int tid = threadIdx.x;
    for (int i = tid; i < 2048; i += 256) w2s[i] = w2frag[i];
    __syncthreads();

    int lane = tid & 63, wv = tid >> 6;
    int r = lane & 15, g = lane >> 4;
    float asw0 = as2[r], asw1 = as2[16 + r], asw2 = as2[32 + r], asw3 = as2[48 + r];
    float adw0 = ad2[r], adw1 = ad2[16 + r], adw2 = ad2[32 + r], adw3 = ad2[48 + r];

    int ntiles = (N + 15) >> 4;
    for (int t = blockIdx.x * 4 + wv; t < ntiles; t += gridDim.x * 4){
        int base = t << 4;
        int nodeA = min(base + r, N - 1);
        const _Float16* ap = h1 + (size_t)nodeA * 256 + 4 * g;
        f32x4 ac0 = {0.f,0.f,0.f,0.f}, ac1 = {0.f,0.f,0.f,0.f};
        f32x4 ac2 = {0.f,0.f,0.f,0.f}, ac3 = {0.f,0.f,0.f,0.f};
#pragma unroll
        for (int s = 0; s < 8; s++){
            uint2 lo = *(const uint2*)(ap + 32 * s);
            uint2 hi = *(const uint2*)(ap + 32 * s + 16);
            union { uint4 u; f16x8 f; } a;
            a.u = make_uint4(lo.x, lo.y, hi.x, hi.y);
            union { uint4 u; f16x8 f; } b0, b1, b2, b3;
            b0.u = w2s[(s * 4 + 0) * 64 + lane];
            b1.u = w2s[(s * 4 + 1) * 64 + lane];
            b2.u = w2s[(s * 4 + 2) * 64 + lane];
            b3.u = w2s[(s * 4 + 3) * 64 + lane];
            ac0 = __builtin_amdgcn_mfma_f32_16x16x32_f16(a.f, b0.f, ac0, 0, 0, 0);
            ac1 = __builtin_amdgcn_mfma_f32_16x16x32_f16(a.f, b1.f, ac1, 0, 0, 0);
            ac2 = __builtin_amdgcn_mfma_f32_16x16x32_f16(a.f, b2.f, ac2, 0, 0, 0);
            ac3 = __builtin_amdgcn_mfma_f32_16x16x32_f16(a.f, b3.f, ac3, 0, 0, 0);
        }
        float ps0 = 0.f, ps1 = 0.f, ps2 = 0.f, ps3 = 0.f;
        float pd0 = 0.f, pd1 = 0.f, pd2 = 0.f, pd3 = 0.f;
#pragma unroll
        for (int reg = 0; reg < 4; reg++){
            int node = base + 4 * g + reg;
            if (node < N){
                size_t rowb = (size_t)node * 64;
                xh2[rowb +      r] = __float2half(ac0[reg]);
                xh2[rowb + 16 + r] = __float2half(ac1[reg]);
                xh2[rowb + 32 + r] = __float2half(ac2[reg]);
                xh2[rowb + 48 + r] = __float2half(ac3[reg]);
            }
            float ps = ac0[reg]*asw0 + ac1[reg]*asw1 + ac2[reg]*asw2 + ac3[reg]*asw3;
            float pd = ac0[reg]*adw0 + ac1[reg]*adw1 + ac2[reg]*adw2 + ac3[reg]*adw3;
            if (reg == 0){ ps0 = ps; pd0 = pd; }
            else if (reg == 1){ ps1 = ps; pd1 = pd; }
            else if (reg == 2){ ps2 = ps; pd2 = pd; }
            else { ps3 = ps; pd3 = pd; }
        }
#pragma unroll
        for (int m = 1; m < 16; m <<= 1){
            ps0 += __shfl_xor(ps0, m, 64); pd0 += __shfl_xor(pd0, m, 64);
            ps1 += __shfl_xor(ps1, m, 64); pd1 += __shfl_xor(pd1, m, 64);
            ps2 += __shfl_xor(ps2, m, 64); pd2 += __shfl_xor(pd2, m, 64);
            ps3 += __shfl_xor(ps3, m, 64); pd3 += __shfl_xor(pd3, m, 64);
        }
        if (r == 0){
            int nb = base + 4 * g;
            if (nb     < N){ asrc[nb    ] = ps0; adst[nb    ] = pd0; }
            if (nb + 1 < N){ asrc[nb + 1] = ps1; adst[nb + 1] = pd1; }
            if (nb + 2 < N){ asrc[nb + 2] = ps2; adst[nb + 2] = pd2; }
            if (nb + 3 < N){ asrc[nb + 3] = ps3; adst[nb + 3] = pd3; }
        }
    }
}

// layer-2 aggregation fused with mean pool, HALF2 EDGE-PAIRED:
// lane = (channel-pair c, half); one dword load fetches TWO edges' rows per
// instruction (half 0 -> edge j, half 1 -> edge j+1). VMEM insts/edge: 3 -> 1.5,
// v_exp/edge halved. fp32 logits & accumulation; halves merged per node via
// 3x shfl_xor(32).
__global__ void k_agg2p(const __half* __restrict__ xh2, const float* __restrict__ asrc,
                        const float* __restrict__ adst, const int* __restrict__ offs,
                        const int* __restrict__ ssrc, const float* __restrict__ b2,
                        const int* __restrict__ batch, int N,
                        float* sums, int* counts){
    int tid = threadIdx.x;
    int lane = tid & 63, wv = tid >> 6;  // 4 waves/block
    int c = lane & 31;     // channel pair: channels 2c, 2c+1
    int half = lane >> 5;  // 0 or 1
    int wid = blockIdx.x * 4 + wv;
    int nw = gridDim.x * 4;
    int chunk = (N + nw - 1) / nw;
    int beg = wid * chunk, end = min(beg + chunk, N);
    if (beg >= end) return;
    const unsigned int* xrow = (const unsigned int*)xh2;   // 32 dwords per row
    float b2a = b2[2 * c], b2b = b2[2 * c + 1];
    float pacc0 = 0.f, pacc1 = 0.f; int pcnt = 0; int cur = batch[beg];
    for (int n = beg; n < end; n++){
        float ad = adst[n];
        float acc0 = 0.f, acc1 = 0.f, den = 0.f;
        int e0 = offs[n], e1 = offs[n + 1];
        int j = e0;
        for (; j + 8 <= e1; j += 8){   // 4 pairs = 8 edges
            int sA = ssrc[j     + half];
            int sB = ssrc[j + 2 + half];
            int sC = ssrc[j + 4 + half];
            int sD = ssrc[j + 6 + half];
            float aA = asrc[sA], aB = asrc[sB], aC = asrc[sC], aD = asrc[sD];
            unsigned int rA = xrow[(size_t)sA * 32 + c];
            unsigned int rB = xrow[(size_t)sB * 32 + c];
            unsigned int rC = xrow[(size_t)sC * 32 + c];
            unsigned int rD = xrow[(size_t)sD * 32 + c];
            float wA = __expf(lrelu(aA + ad));
            float wB = __expf(lrelu(aB + ad));
            float wC = __expf(lrelu(aC + ad));
            float wD = __expf(lrelu(aD + ad));
            float2 fA = __half22float2(*(const __half2*)&rA);
            float2 fB = __half22float2(*(const __half2*)&rB);
            float2 fC = __half22float2(*(const __half2*)&rC);
            float2 fD = __half22float2(*(const __half2*)&rD);
            acc0 += wA * fA.x + wB * fB.x + wC * fC.x + wD * fD.x;
            acc1 += wA * fA.y + wB * fB.y + wC * fC.y + wD * fD.y;
            den  += wA + wB + wC + wD;
        }
        for (; j + 2 <= e1; j += 2){   // single pair
            int s = ssrc[j + half];
            float a = asrc[s];
            unsigned int r = xrow[(size_t)s * 32 + c];
            float w = __expf(lrelu(a + ad));
            float2 f = __half22float2(*(const __half2*)&r);
            acc0 += w * f.x;
            acc1 += w * f.y;
            den  += w;
        }
        if (j < e1){                   // odd tail: half 1 contributes zero
            int s = ssrc[j];
            float w = (half == 0) ? __expf(lrelu(asrc[s] + ad)) : 0.f;
            unsigned int r = xrow[(size_t)s * 32 + c];
            float2 f = __half22float2(*(const __half2*)&r);
            acc0 += w * f.x;
            acc1 += w * f.y;
            den  += w;
        }
        // merge halves (even edges in half0, odd in half1)
        acc0 += __shfl_xor(acc0, 32, 64);
        acc1 += __shfl_xor(acc1, 32, 64);
        den  += __shfl_xor(den, 32, 64);
        float h2a = elu_(acc0 / den + b2a);
        float h2b = elu_(acc1 / den + b2b);
        int g = batch[n];
        if (g != cur){
            if (half == 0){
                atomicAdd(&sums[cur * HID + 2 * c    ], pacc0);
                atomicAdd(&sums[cur * HID + 2 * c + 1], pacc1);
            }
            if (lane == 0) atomicAdd(&counts[cur], pcnt);
            pacc0 = 0.f; pacc1 = 0.f; pcnt = 0; cur = g;
        }
        pacc0 += h2a; pacc1 += h2b; pcnt++;
    }
    if (half == 0){
        atomicAdd(&sums[cur * HID + 2 * c    ], pacc0);
        atomicAdd(&sums[cur * HID + 2 * c + 1], pacc1);
    }
    if (lane == 0) atomicAdd(&counts[cur], pcnt);
}

__global__ void k_final(const float* __restrict__ sums, const int* __restrict__ counts,
                        const float* __restrict__ Wl, const float* __restrict__ bl,
                        float* out){
    int t = threadIdx.x;
    if (t >= GR * 2) return;
    int g = t >> 1, task = t & 1;
    float c = (float)max(counts[g], 1);
    float acc = 0.f;
#pragma unroll
    for (int k = 0; k < HID; k++)
        acc += (sums[g * HID + k] / c) * Wl[k * 2 + task];
    out[t] = acc + bl[task];
}

extern "C" void kernel_launch(void* const* d_in, const int* in_sizes, int n_in,
                              void* d_out, int out_size, void* d_ws, size_t ws_size,
                              hipStream_t stream) {
    const float* x    = (const float*)d_in[0];
    const int*   ei   = (const int*)  d_in[1];
    const int*   batch= (const int*)  d_in[2];
    const float* W1   = (const float*)d_in[3];
    const float* as1  = (const float*)d_in[4];
    const float* ad1  = (const float*)d_in[5];
    const float* b1   = (const float*)d_in[6];
    const float* W2   = (const float*)d_in[7];
    const float* as2  = (const float*)d_in[8];
    const float* ad2  = (const float*)d_in[9];
    const float* b2   = (const float*)d_in[10];
    const float* Wl   = (const float*)d_in[11];
    const float* bl   = (const float*)d_in[12];
    float* out = (float*)d_out;

    int N  = in_sizes[0] / 2;
    int E  = in_sizes[1] / 2;
    int Et = E + N;
    const int* srcp = ei;
    const int* dstp = ei + E;

    char* p = (char*)d_ws;
    auto alloc = [&](size_t bytes)->char* {
        char* r = p; p += (bytes + 255) & ~(size_t)255; return r;
    };
    int*    offs   = (int*)   alloc((size_t)(N + 1) * 4);
    int*    bcnt   = (int*)   alloc(NBKT_MAX * 4);
    int*    bbase  = (int*)   alloc((NBKT_MAX + 1) * 4);
    int*    bcursor= (int*)   alloc(NBKT_MAX * 4);
    int*    ssrc   = (int*)   alloc((size_t)Et * 4);
    unsigned int* tmp = (unsigned int*)alloc((size_t)E * 4);
    float*  cvec   = (float*) alloc(16 * 4);
    float4* Sa     = (float4*)alloc((size_t)N * 16);
    float4* Sb     = (float4*)alloc((size_t)N * 16);
    float4* Sc     = (float4*)alloc((size_t)N * 16);
    float*  asrc2  = (float*) alloc((size_t)N * 4);
    float*  adst2  = (float*) alloc((size_t)N * 4);
    float*  sums   = (float*) alloc((size_t)GR * HID * 4);
    int*    counts = (int*)   alloc((size_t)GR * 4);
    uint4*  w2frag = (uint4*) alloc(2048 * 16);
    _Float16* h1f  = (_Float16*)alloc((size_t)N * 256 * 2);
    __half* xh2    = (__half*)alloc((size_t)N * 64 * 2);

    int nbkt = (N + 255) >> BK_SH;

    k_init  <<<16, 256, 0, stream>>>(sums, counts, bcnt, W1, as1, ad1, cvec);
    k_w2frag<<<8, 256, 0, stream>>>(W2, w2frag);
    k_histB <<<256, 256, 0, stream>>>(dstp, E, bcnt);
    k_bscan <<<1, NBKT_MAX, 0, stream>>>(bcnt, bbase, bcursor);
    k_part  <<<(E + PART_T - 1) / PART_T, 256, 0, stream>>>(srcp, dstp, E, bcursor, tmp);
    k_csr2  <<<nbkt, 256, 0, stream>>>(tmp, bbase, N, Et, offs, ssrc);

    k_agg1s <<<(N + 255) / 256, 256, 0, stream>>>(x, offs, ssrc, cvec, N, Sa, Sb, Sc);
    k_h1f16 <<<(N * 64 + 255) / 256, 256, 0, stream>>>((const float*)Sa, (const float*)Sb,
                                                       (const float*)Sc, W1, b1, N, h1f);
    k_mfma  <<<1024, 256, 0, stream>>>(h1f, w2frag, as2, ad2, N, xh2, asrc2, adst2);
    k_agg2p <<<2048, 256, 0, stream>>>(xh2, asrc2, adst2, offs, ssrc, b2,
                                       batch, N, sums, counts);
    k_final <<<1, 128, 0, stream>>>(sums, counts, Wl, bl, out);
}

// Round 11
// 201.328 us; speedup vs baseline: 1.8495x; 1.0611x over previous
//
#include <hip/hip_runtime.h>
#include <hip/hip_fp16.h>
#include <math.h>

#define HID 64
#define HEADS 4
#define GR 64
#define NEG 0.2f
#define NBKT_MAX 512
#define BK_SH 8     // 256 nodes per bucket
#define PART_T 2048 // edges per partition tile
// tmp edge pack: (dst & 255) << 17 | src   -- requires N < 2^17 (N=100000 ok)

typedef _Float16 f16x8 __attribute__((ext_vector_type(8)));
typedef float    f32x4 __attribute__((ext_vector_type(4)));

__device__ __forceinline__ float lrelu(float v){ return v > 0.f ? v : NEG * v; }
__device__ __forceinline__ float elu_(float v){ return v > 0.f ? v : __expf(v) - 1.f; }

// zero pooled sums/counts/bucket-counts; block 0 wave 0 also computes the
// attention-projection constants cvec = [cs0(4), cs1(4), cd0(4), cd1(4)].
// (must run EVERY call: harness does not re-poison ws between timed replays)
__global__ void k_init(float* sums, int* counts, int* bcnt,
                       const float* __restrict__ W1, const float* __restrict__ as1,
                       const float* __restrict__ ad1, float* cvec){
    int i = blockIdx.x * blockDim.x + threadIdx.x;
    if (i < GR * HID) sums[i] = 0.f;
    if (i < GR) counts[i] = 0;
    if (i < NBKT_MAX) bcnt[i] = 0;
    if (blockIdx.x == 0 && threadIdx.x < 64){
        int lane = threadIdx.x;
#pragma unroll
        for (int h = 0; h < HEADS; h++){
            int j = h * HID + lane;
            float s0 = W1[j]       * as1[j];
            float s1 = W1[256 + j] * as1[j];
            float d0 = W1[j]       * ad1[j];
            float d1 = W1[256 + j] * ad1[j];
#pragma unroll
            for (int off = 32; off; off >>= 1){
                s0 += __shfl_xor(s0, off, 64);
                s1 += __shfl_xor(s1, off, 64);
                d0 += __shfl_xor(d0, off, 64);
                d1 += __shfl_xor(d1, off, 64);
            }
            if (lane == 0){
                cvec[h] = s0; cvec[4 + h] = s1; cvec[8 + h] = d0; cvec[12 + h] = d1;
            }
        }
    }
}

// merged: blocks 0..255 bucket histogram; blocks 256..263 pack W2 fragments.
// w2frag[s][c][lane] elem e -> k = 32s + 4*(lane>>4) + (e&3) + 16*(e>>2),
// col = 16c + (lane&15).
__global__ void k_histW(const int* __restrict__ dst, int E, int* bcnt,
                        const float* __restrict__ W2, uint4* __restrict__ w2frag){
    __shared__ int bh[NBKT_MAX];
    if (blockIdx.x < 256){
        for (int b = threadIdx.x; b < NBKT_MAX; b += blockDim.x) bh[b] = 0;
        __syncthreads();
        int stride = 256 * blockDim.x;
        for (int i = blockIdx.x * blockDim.x + threadIdx.x; i < E; i += stride)
            atomicAdd(&bh[dst[i] >> BK_SH], 1);
        __syncthreads();
        for (int b = threadIdx.x; b < NBKT_MAX; b += blockDim.x)
            if (bh[b]) atomicAdd(&bcnt[b], bh[b]);
    } else {
        int t = (blockIdx.x - 256) * 256 + threadIdx.x;
        if (t < 2048){
            int lane = t & 63, c = (t >> 6) & 3, s = t >> 8;
            union { uint4 u; _Float16 h[8]; } o;
#pragma unroll
            for (int e = 0; e < 8; e++){
                int k = 32 * s + 4 * (lane >> 4) + (e & 3) + 16 * (e >> 2);
                int col = 16 * c + (lane & 15);
                o.h[e] = (_Float16)W2[k * 64 + col];
            }
            w2frag[t] = o.u;
        }
    }
}

// exclusive scan of bucket counts -> bucket bases + partition cursors.
__global__ void k_bscan(const int* __restrict__ bcnt, int* bbase, int* bcursor){
    __shared__ int sh[NBKT_MAX];
    int t = threadIdx.x;     // 512 threads
    int v = bcnt[t];
    sh[t] = v;
    __syncthreads();
    for (int off = 1; off < NBKT_MAX; off <<= 1){
        int u = (t >= off) ? sh[t - off] : 0;
        __syncthreads();
        sh[t] += u;
        __syncthreads();
    }
    bbase[t] = sh[t] - v;
    bcursor[t] = sh[t] - v;
    if (t == NBKT_MAX - 1) bbase[NBKT_MAX] = sh[t];
}

// staged partition: per-tile LDS bucket count -> one global reserve per
// (block,bucket) -> scatter packed u32 (dloc<<17|src) into block-private runs.
__global__ void __launch_bounds__(256)
k_part(const int* __restrict__ src, const int* __restrict__ dst, int E,
       int* bcursor, unsigned int* __restrict__ tmp){
    __shared__ int bh[NBKT_MAX];
    __shared__ int gbl[NBKT_MAX];
    int tid = threadIdx.x;
    int base = blockIdx.x * PART_T;
    for (int b = tid; b < NBKT_MAX; b += 256) bh[b] = 0;
    __syncthreads();
#pragma unroll
    for (int r = 0; r < PART_T / 256; r++){
        int i = base + r * 256 + tid;
        if (i < E) atomicAdd(&bh[dst[i] >> BK_SH], 1);
    }
    __syncthreads();
    for (int b = tid; b < NBKT_MAX; b += 256){
        int c = bh[b];
        gbl[b] = c ? atomicAdd(&bcursor[b], c) : 0;
        bh[b] = 0;
    }
    __syncthreads();
#pragma unroll
    for (int r = 0; r < PART_T / 256; r++){
        int i = base + r * 256 + tid;
        if (i < E){
            int s = src[i], d = dst[i];
            int b = d >> BK_SH;
            int rank = atomicAdd(&bh[b], 1);
            tmp[(size_t)(gbl[b] + rank)] =
                ((unsigned)(d & ((1 << BK_SH) - 1)) << 17) | (unsigned)s;
        }
    }
}

// per-bucket CSR emit, deriving per-node offs locally:
// offs[n] = bbase[b] + n0 + excl_scan_local(deg_local+1)
__global__ void __launch_bounds__(256)
k_csr2(const unsigned int* __restrict__ tmp, const int* __restrict__ bbase,
       int N, int Et, int* __restrict__ offs, int* __restrict__ ssrc){
    __shared__ int degl[256];
    __shared__ int rc[256];
    __shared__ int scan[256];
    __shared__ int ofl[256];
    int b = blockIdx.x, tid = threadIdx.x;
    int n0 = b << BK_SH;
    int nloc = min(256, N - n0);
    degl[tid] = 0; rc[tid] = 0;
    __syncthreads();
    int beg = bbase[b], cnt = bbase[b + 1] - beg;
    for (int i = tid; i < cnt; i += 256)
        atomicAdd(&degl[tmp[beg + i] >> 17], 1);
    __syncthreads();
    int v = (tid < nloc) ? degl[tid] + 1 : 0;
    scan[tid] = v;
    __syncthreads();
    for (int off = 1; off < 256; off <<= 1){
        int u = (tid >= off) ? scan[tid - off] : 0;
        __syncthreads();
        scan[tid] += u;
        __syncthreads();
    }
    int base = beg + n0;
    if (tid < nloc){
        int o = base + scan[tid] - v;   // exclusive
        ofl[tid] = o;
        offs[n0 + tid] = o;
        ssrc[o] = n0 + tid;             // self-loop first
    }
    if (b == 0 && tid == 0) offs[N] = Et;
    __syncthreads();
    for (int i = tid; i < cnt; i += 256){
        unsigned int e = tmp[beg + i];
        int dloc = (int)(e >> 17);
        int s = (int)(e & 0x1FFFFu);
        int pos = ofl[dloc] + 1 + atomicAdd(&rc[dloc], 1);
        ssrc[pos] = s;
    }
}

// layer-1 aggregation via rank-2 trick: thread per dst node, gather only x[src]
// (8B/edge, cache-resident). Edge loop unrolled x8 for per-lane MLP.
__global__ void k_agg1s(const float* __restrict__ x, const int* __restrict__ offs,
                        const int* __restrict__ ssrc, const float* __restrict__ cvec,
                        int N, float4* Sa, float4* Sb, float4* Sc){
    int n = blockIdx.x * blockDim.x + threadIdx.x;
    if (n >= N) return;
    float4 cs0 = ((const float4*)cvec)[0];
    float4 cs1 = ((const float4*)cvec)[1];
    float4 cd0 = ((const float4*)cvec)[2];
    float4 cd1 = ((const float4*)cvec)[3];
    float c0[4] = {cs0.x, cs0.y, cs0.z, cs0.w};
    float c1[4] = {cs1.x, cs1.y, cs1.z, cs1.w};
    float2 xn = ((const float2*)x)[n];
    float ad[4] = {xn.x*cd0.x + xn.y*cd1.x, xn.x*cd0.y + xn.y*cd1.y,
                   xn.x*cd0.z + xn.y*cd1.z, xn.x*cd0.w + xn.y*cd1.w};
    float A0[4] = {0,0,0,0}, A1[4] = {0,0,0,0}, D[4] = {0,0,0,0};
    int beg = offs[n], end = offs[n + 1];
    int j = beg;
    for (; j + 8 <= end; j += 8){
        int si[8];
#pragma unroll
        for (int u = 0; u < 8; u++) si[u] = ssrc[j + u];
        float2 xs[8];
#pragma unroll
        for (int u = 0; u < 8; u++) xs[u] = ((const float2*)x)[si[u]];
#pragma unroll
        for (int h = 0; h < HEADS; h++){
#pragma unroll
            for (int u = 0; u < 8; u++){
                float w = __expf(lrelu(xs[u].x * c0[h] + xs[u].y * c1[h] + ad[h]));
                A0[h] += w * xs[u].x;
                A1[h] += w * xs[u].y;
                D[h]  += w;
            }
        }
    }
    if (j + 4 <= end){
        int si[4];
#pragma unroll
        for (int u = 0; u < 4; u++) si[u] = ssrc[j + u];
        float2 xs[4];
#pragma unroll
        for (int u = 0; u < 4; u++) xs[u] = ((const float2*)x)[si[u]];
#pragma unroll
        for (int h = 0; h < HEADS; h++){
#pragma unroll
            for (int u = 0; u < 4; u++){
                float w = __expf(lrelu(xs[u].x * c0[h] + xs[u].y * c1[h] + ad[h]));
                A0[h] += w * xs[u].x;
                A1[h] += w * xs[u].y;
                D[h]  += w;
            }
        }
        j += 4;
    }
    for (; j < end; j++){
        int s = ssrc[j];
        float2 xs = ((const float2*)x)[s];
#pragma unroll
        for (int h = 0; h < HEADS; h++){
            float e = xs.x * c0[h] + xs.y * c1[h] + ad[h];
            float w = __expf(lrelu(e));
            A0[h] += w * xs.x;
            A1[h] += w * xs.y;
            D[h]  += w;
        }
    }
    Sa[n] = make_float4(A0[0], A0[1], A0[2], A0[3]);
    Sb[n] = make_float4(A1[0], A1[1], A1[2], A1[3]);
    Sc[n] = make_float4(D[0],  D[1],  D[2],  D[3]);
}

// Fused MFMA layer-2 GEMM: A-fragments (h1 rows) computed IN-REGISTER from
// the 12 per-node scalars (no h1 materialization; saves 102 MB of traffic).
// head index (32s+4g+e)>>6 == s>>1 is compile-time; W1/b1 staged in LDS.
// k-map of A == k-map of B fragments (verified R9/R10 numerics preserved).
__global__ void __launch_bounds__(256)
k_mfma(const float4* __restrict__ Sa4, const float4* __restrict__ Sb4,
       const float4* __restrict__ Sc4, const float* __restrict__ W1,
       const float* __restrict__ b1, const uint4* __restrict__ w2frag,
       const float* __restrict__ as2, const float* __restrict__ ad2,
       int N, __half* __restrict__ xh2, float* __restrict__ asrc,
       float* __restrict__ adst){
    __shared__ uint4 w2s[2048];                      // 32 KB B fragments
    __shared__ float4 w1aS[64], w1bS[64], b1S[64];   // 3 KB W1 rows + b1
    int tid = threadIdx.x;
    for (int i = tid; i < 2048; i += 256) w2s[i] = w2frag[i];
    if (tid < 64){
        w1aS[tid] = ((const float4*)W1)[tid];        // W1[0][4t..4t+3]
        w1bS[tid] = ((const float4*)W1)[tid + 64];   // W1[1][...]
        b1S[tid]  = ((const float4*)b1)[tid];
    }
    __syncthreads();

    int lane = tid & 63, wv = tid >> 6;
    int r = lane & 15, g = lane >> 4;
    float asw0 = as2[r], asw1 = as2[16 + r], asw2 = as2[32 + r], asw3 = as2[48 + r];
    float adw0 = ad2[r], adw1 = ad2[16 + r], adw2 = ad2[32 + r], adw3 = ad2[48 + r];

    int ntiles = (N + 15) >> 4;
    for (int t = blockIdx.x * 4 + wv; t < ntiles; t += gridDim.x * 4){
        int base = t << 4;
        int nodeA = min(base + r, N - 1);
        float4 sa = Sa4[nodeA], sb = Sb4[nodeA], sc = Sc4[nodeA];
        float rdv0 = 1.0f / sc.x, rdv1 = 1.0f / sc.y;
        float rdv2 = 1.0f / sc.z, rdv3 = 1.0f / sc.w;
        f32x4 ac0 = {0.f,0.f,0.f,0.f}, ac1 = {0.f,0.f,0.f,0.f};
        f32x4 ac2 = {0.f,0.f,0.f,0.f}, ac3 = {0.f,0.f,0.f,0.f};
#pragma unroll
        for (int s = 0; s < 8; s++){
            const int head = s >> 1;                 // compile-time
            float A0 = head == 0 ? sa.x : head == 1 ? sa.y : head == 2 ? sa.z : sa.w;
            float A1 = head == 0 ? sb.x : head == 1 ? sb.y : head == 2 ? sb.z : sb.w;
            float rd = head == 0 ? rdv0 : head == 1 ? rdv1 : head == 2 ? rdv2 : rdv3;
            int q0 = 8 * s + g;
            float4 w0lo = w1aS[q0], w0hi = w1aS[q0 + 4];
            float4 w1lo = w1bS[q0], w1hi = w1bS[q0 + 4];
            float4 blo  = b1S[q0],  bhi  = b1S[q0 + 4];
            union { uint4 u; f16x8 f; _Float16 h[8]; } a;
            a.h[0] = (_Float16)elu_((A0 * w0lo.x + A1 * w1lo.x) * rd + blo.x);
            a.h[1] = (_Float16)elu_((A0 * w0lo.y + A1 * w1lo.y) * rd + blo.y);
            a.h[2] = (_Float16)elu_((A0 * w0lo.z + A1 * w1lo.z) * rd + blo.z);
            a.h[3] = (_Float16)elu_((A0 * w0lo.w + A1 * w1lo.w) * rd + blo.w);
            a.h[4] = (_Float16)elu_((A0 * w0hi.x + A1 * w1hi.x) * rd + bhi.x);
            a.h[5] = (_Float16)elu_((A0 * w0hi.y + A1 * w1hi.y) * rd + bhi.y);
            a.h[6] = (_Float16)elu_((A0 * w0hi.z + A1 * w1hi.z) * rd + bhi.z);
            a.h[7] = (_Float16)elu_((A0 * w0hi.w + A1 * w1hi.w) * rd + bhi.w);
            union { uint4 u; f16x8 f; } b0, b1x, b2, b3;
            b0.u  = w2s[(s * 4 + 0) * 64 + lane];
            b1x.u = w2s[(s * 4 + 1) * 64 + lane];
            b2.u  = w2s[(s * 4 + 2) * 64 + lane];
            b3.u  = w2s[(s * 4 + 3) * 64 + lane];
            ac0 = __builtin_amdgcn_mfma_f32_16x16x32_f16(a.f, b0.f,  ac0, 0, 0, 0);
            ac1 = __builtin_amdgcn_mfma_f32_16x16x32_f16(a.f, b1x.f, ac1, 0, 0, 0);
            ac2 = __builtin_amdgcn_mfma_f32_16x16x32_f16(a.f, b2.f,  ac2, 0, 0, 0);
            ac3 = __builtin_amdgcn_mfma_f32_16x16x32_f16(a.f, b3.f,  ac3, 0, 0, 0);
        }
        float ps0 = 0.f, ps1 = 0.f, ps2 = 0.f, ps3 = 0.f;
        float pd0 = 0.f, pd1 = 0.f, pd2 = 0.f, pd3 = 0.f;
#pragma unroll
        for (int reg = 0; reg < 4; reg++){
            int node = base + 4 * g + reg;
            if (node < N){
                size_t rowb = (size_t)node * 64;
                xh2[rowb +      r] = __float2half(ac0[reg]);
                xh2[rowb + 16 + r] = __float2half(ac1[reg]);
                xh2[rowb + 32 + r] = __float2half(ac2[reg]);
                xh2[rowb + 48 + r] = __float2half(ac3[reg]);
            }
            float ps = ac0[reg]*asw0 + ac1[reg]*asw1 + ac2[reg]*asw2 + ac3[reg]*asw3;
            float pd = ac0[reg]*adw0 + ac1[reg]*adw1 + ac2[reg]*adw2 + ac3[reg]*adw3;
            if (reg == 0){ ps0 = ps; pd0 = pd; }
            else if (reg == 1){ ps1 = ps; pd1 = pd; }
            else if (reg == 2){ ps2 = ps; pd2 = pd; }
            else { ps3 = ps; pd3 = pd; }
        }
#pragma unroll
        for (int m = 1; m < 16; m <<= 1){
            ps0 += __shfl_xor(ps0, m, 64); pd0 += __shfl_xor(pd0, m, 64);
            ps1 += __shfl_xor(ps1, m, 64); pd1 += __shfl_xor(pd1, m, 64);
            ps2 += __shfl_xor(ps2, m, 64); pd2 += __shfl_xor(pd2, m, 64);
            ps3 += __shfl_xor(ps3, m, 64); pd3 += __shfl_xor(pd3, m, 64);
        }
        if (r == 0){
            int nb = base + 4 * g;
            if (nb     < N){ asrc[nb    ] = ps0; adst[nb    ] = pd0; }
            if (nb + 1 < N){ asrc[nb + 1] = ps1; adst[nb + 1] = pd1; }
            if (nb + 2 < N){ asrc[nb + 2] = ps2; adst[nb + 2] = pd2; }
            if (nb + 3 < N){ asrc[nb + 3] = ps3; adst[nb + 3] = pd3; }
        }
    }
}

// layer-2 aggregation fused with mean pool, half2 edge-paired, unrolled to
// 16 edges (8 pairs) for ~24 in-flight VMEM per lane (covers L3 latency).
__global__ void k_agg2p(const __half* __restrict__ xh2, const float* __restrict__ asrc,
                        const float* __restrict__ adst, const int* __restrict__ offs,
                        const int* __restrict__ ssrc, const float* __restrict__ b2,
                        const int* __restrict__ batch, int N,
                        float* sums, int* counts){
    int tid = threadIdx.x;
    int lane = tid & 63, wv = tid >> 6;  // 4 waves/block
    int c = lane & 31;     // channel pair: channels 2c, 2c+1
    int half = lane >> 5;  // 0 or 1
    int wid = blockIdx.x * 4 + wv;
    int nw = gridDim.x * 4;
    int chunk = (N + nw - 1) / nw;
    int beg = wid * chunk, end = min(beg + chunk, N);
    if (beg >= end) return;
    const unsigned int* xrow = (const unsigned int*)xh2;   // 32 dwords per row
    float b2a = b2[2 * c], b2b = b2[2 * c + 1];
    float pacc0 = 0.f, pacc1 = 0.f; int pcnt = 0; int cur = batch[beg];
    for (int n = beg; n < end; n++){
        float ad = adst[n];
        float acc0 = 0.f, acc1 = 0.f, den = 0.f;
        int e0 = offs[n], e1 = offs[n + 1];
        int j = e0;
        for (; j + 16 <= e1; j += 16){  // 8 pairs = 16 edges
            int si[8];
#pragma unroll
            for (int u = 0; u < 8; u++) si[u] = ssrc[j + 2 * u + half];
            float av[8];
#pragma unroll
            for (int u = 0; u < 8; u++) av[u] = asrc[si[u]];
            unsigned int rv[8];
#pragma unroll
            for (int u = 0; u < 8; u++) rv[u] = xrow[(size_t)si[u] * 32 + c];
#pragma unroll
            for (int u = 0; u < 8; u++){
                float w = __expf(lrelu(av[u] + ad));
                float2 f = __half22float2(*(const __half2*)&rv[u]);
                acc0 += w * f.x;
                acc1 += w * f.y;
                den  += w;
            }
        }
        if (j + 8 <= e1){              // 4 pairs
            int si[4];
#pragma unroll
            for (int u = 0; u < 4; u++) si[u] = ssrc[j + 2 * u + half];
            float av[4];
#pragma unroll
            for (int u = 0; u < 4; u++) av[u] = asrc[si[u]];
            unsigned int rv[4];
#pragma unroll
            for (int u = 0; u < 4; u++) rv[u] = xrow[(size_t)si[u] * 32 + c];
#pragma unroll
            for (int u = 0; u < 4; u++){
                float w = __expf(lrelu(av[u] + ad));
                float2 f = __half22float2(*(const __half2*)&rv[u]);
                acc0 += w * f.x;
                acc1 += w * f.y;
                den  += w;
            }
            j += 8;
        }
        for (; j + 2 <= e1; j += 2){   // single pair
            int s = ssrc[j + half];
            float a = asrc[s];
            unsigned int rr = xrow[(size_t)s * 32 + c];
            float w = __expf(lrelu(a + ad));
            float2 f = __half22float2(*(const __half2*)&rr);
            acc0 += w * f.x;
            acc1 += w * f.y;
            den  += w;
        }
        if (j < e1){                   // odd tail: half 1 contributes zero
            int s = ssrc[j];
            float w = (half == 0) ? __expf(lrelu(asrc[s] + ad)) : 0.f;
            unsigned int rr = xrow[(size_t)s * 32 + c];
            float2 f = __half22float2(*(const __half2*)&rr);
            acc0 += w * f.x;
            acc1 += w * f.y;
            den  += w;
        }
        acc0 += __shfl_xor(acc0, 32, 64);
        acc1 += __shfl_xor(acc1, 32, 64);
        den  += __shfl_xor(den, 32, 64);
        float h2a = elu_(acc0 / den + b2a);
        float h2b = elu_(acc1 / den + b2b);
        int g = batch[n];
        if (g != cur){
            if (half == 0){
                atomicAdd(&sums[cur * HID + 2 * c    ], pacc0);
                atomicAdd(&sums[cur * HID + 2 * c + 1], pacc1);
            }
            if (lane == 0) atomicAdd(&counts[cur], pcnt);
            pacc0 = 0.f; pacc1 = 0.f; pcnt = 0; cur = g;
        }
        pacc0 += h2a; pacc1 += h2b; pcnt++;
    }
    if (half == 0){
        atomicAdd(&sums[cur * HID + 2 * c    ], pacc0);
        atomicAdd(&sums[cur * HID + 2 * c + 1], pacc1);
    }
    if (lane == 0) atomicAdd(&counts[cur], pcnt);
}

__global__ void k_final(const float* __restrict__ sums, const int* __restrict__ counts,
                        const float* __restrict__ Wl, const float* __restrict__ bl,
                        float* out){
    int t = threadIdx.x;
    if (t >= GR * 2) return;
    int g = t >> 1, task = t & 1;
    float c = (float)max(counts[g], 1);
    float acc = 0.f;
#pragma unroll
    for (int k = 0; k < HID; k++)
        acc += (sums[g * HID + k] / c) * Wl[k * 2 + task];
    out[t] = acc + bl[task];
}

extern "C" void kernel_launch(void* const* d_in, const int* in_sizes, int n_in,
                              void* d_out, int out_size, void* d_ws, size_t ws_size,
                              hipStream_t stream) {
    const float* x    = (const float*)d_in[0];
    const int*   ei   = (const int*)  d_in[1];
    const int*   batch= (const int*)  d_in[2];
    const float* W1   = (const float*)d_in[3];
    const float* as1  = (const float*)d_in[4];
    const float* ad1  = (const float*)d_in[5];
    const float* b1   = (const float*)d_in[6];
    const float* W2   = (const float*)d_in[7];
    const float* as2  = (const float*)d_in[8];
    const float* ad2  = (const float*)d_in[9];
    const float* b2   = (const float*)d_in[10];
    const float* Wl   = (const float*)d_in[11];
    const float* bl   = (const float*)d_in[12];
    float* out = (float*)d_out;

    int N  = in_sizes[0] / 2;
    int E  = in_sizes[1] / 2;
    int Et = E + N;
    const int* srcp = ei;
    const int* dstp = ei + E;

    char* p = (char*)d_ws;
    auto alloc = [&](size_t bytes)->char* {
        char* r = p; p += (bytes + 255) & ~(size_t)255; return r;
    };
    int*    offs   = (int*)   alloc((size_t)(N + 1) * 4);
    int*    bcnt   = (int*)   alloc(NBKT_MAX * 4);
    int*    bbase  = (int*)   alloc((NBKT_MAX + 1) * 4);
    int*    bcursor= (int*)   alloc(NBKT_MAX * 4);
    int*    ssrc   = (int*)   alloc((size_t)Et * 4);
    unsigned int* tmp = (unsigned int*)alloc((size_t)E * 4);
    float*  cvec   = (float*) alloc(16 * 4);
    float4* Sa     = (float4*)alloc((size_t)N * 16);
    float4* Sb     = (float4*)alloc((size_t)N * 16);
    float4* Sc     = (float4*)alloc((size_t)N * 16);
    float*  asrc2  = (float*) alloc((size_t)N * 4);
    float*  adst2  = (float*) alloc((size_t)N * 4);
    float*  sums   = (float*) alloc((size_t)GR * HID * 4);
    int*    counts = (int*)   alloc((size_t)GR * 4);
    uint4*  w2frag = (uint4*) alloc(2048 * 16);
    __half* xh2    = (__half*)alloc((size_t)N * 64 * 2);

    int nbkt = (N + 255) >> BK_SH;

    k_init <<<16, 256, 0, stream>>>(sums, counts, bcnt, W1, as1, ad1, cvec);
    k_histW<<<264, 256, 0, stream>>>(dstp, E, bcnt, W2, w2frag);
    k_bscan<<<1, NBKT_MAX, 0, stream>>>(bcnt, bbase, bcursor);
    k_part <<<(E + PART_T - 1) / PART_T, 256, 0, stream>>>(srcp, dstp, E, bcursor, tmp);
    k_csr2 <<<nbkt, 256, 0, stream>>>(tmp, bbase, N, Et, offs, ssrc);

    k_agg1s<<<(N + 255) / 256, 256, 0, stream>>>(x, offs, ssrc, cvec, N, Sa, Sb, Sc);
    k_mfma <<<1024, 256, 0, stream>>>(Sa, Sb, Sc, W1, b1, w2frag, as2, ad2,
                                      N, xh2, asrc2, adst2);
    k_agg2p<<<2048, 256, 0, stream>>>(xh2, asrc2, adst2, offs, ssrc, b2,
                                      batch, N, sums, counts);
    k_final<<<1, 128, 0, stream>>>(sums, counts, Wl, bl, out);
}